// Round 9
// baseline (272.901 us; speedup 1.0000x reference)
//
#include <hip/hip_runtime.h>
#include <math.h>

#define NN 50000
#define HID 128
#define NG 64
#define BN_EPS 1e-5f

typedef __attribute__((ext_vector_type(8))) short short8;
typedef __attribute__((ext_vector_type(4))) float f32x4;

// ---- bf16 pack/unpack (RNE) ----
__device__ inline unsigned pack_bf2(float a, float b) {
    union { float f; unsigned u; } ua, ub;
    ua.f = a; ub.f = b;
    unsigned x = ua.u, y = ub.u;
    x += 0x7fffu + ((x >> 16) & 1u);
    y += 0x7fffu + ((y >> 16) & 1u);
    return (x >> 16) | (y & 0xffff0000u);
}
__device__ inline unsigned short bf16_1(float x) {
    union { float f; unsigned u; } v;
    v.f = x;
    unsigned r = v.u + 0x7fffu + ((v.u >> 16) & 1u);
    return (unsigned short)(r >> 16);
}
__device__ inline float2 unpack_bf2(unsigned v) {
    union { unsigned u; float f; } a, b;
    a.u = v << 16;
    b.u = v & 0xffff0000u;
    return make_float2(a.f, b.f);
}

// =============== CSR build — radix-style, NO global atomics ===============
// K = 256 nodes/bucket (pow2: bkt = d>>8, ld = d&255 — no int division).
// Phase 1 (hist): per edge-tile per-bucket counts -> hist[k][b].
// Phase 2 (scan): exclusive scan over tiles per bucket -> absolute off[k][b],
//                 bucket totals -> bcurP. Replaces the 391-deep serialized
//                 same-address atomicAdd chain (R3: 95us at 2.5% VALUBusy).
// Phase 3 (scatter): LDS counting sort + coalesced flush at off[k][b].
#define NBKT 256                 // scan width (buckets used = NB <= 256)
#define ETILE 4096
#define EPT   (ETILE / 256)      // 16 edges per thread
#define CAP   10240              // avg bucket load 8192; +25% headroom
#define ASTR 136

// prep: blocks 0..255 W transpose+bf16; block 256 seed logits
__global__ __launch_bounds__(128) void k_prep0(const float* __restrict__ W1,
                                               const float* __restrict__ W2,
                                               unsigned short* __restrict__ wt1,
                                               unsigned short* __restrict__ wt2,
                                               const float* __restrict__ cls_b,
                                               float* __restrict__ logits) {
    int b = blockIdx.x;
    int t = threadIdx.x;
    if (b < 256) {
        int k = b & 127;
        const float* W = (b < 128) ? W1 : W2;
        unsigned short* wt = (b < 128) ? wt1 : wt2;
        wt[t * 128 + k] = bf16_1(W[k * 128 + t]);
    } else {
        if (t < NG) logits[t] = cls_b[0];
    }
}

// ---- shared gemm1 tile body: z[row0..row0+64) = bf16(x@W1), UNSCALED ----
__device__ __forceinline__ void gemm1_tile(char* smem, int row0,
                                           const float* __restrict__ x,
                                           const unsigned short* __restrict__ wt1,
                                           unsigned short* __restrict__ zb,
                                           int n, int t) {
    typedef unsigned short ArowT[ASTR];
    ArowT* A = (ArowT*)smem;
    #pragma unroll
    for (int i = 0; i < 8; ++i) {
        int idx = t + i * 256;
        int r = idx >> 5;
        int c4 = (idx & 31) * 4;
        float4 v = make_float4(0.f, 0.f, 0.f, 0.f);
        if (row0 + r < n) v = *(const float4*)&x[(size_t)(row0 + r) * 128 + c4];
        uint2 p;
        p.x = pack_bf2(v.x, v.y);
        p.y = pack_bf2(v.z, v.w);
        *(uint2*)&A[r][c4] = p;
    }
    __syncthreads();
    int lane = t & 63;
    int wave = t >> 6;
    int m = lane & 15;
    int quad = lane >> 4;
    int r0 = wave * 16;
    short8 a[4];
    #pragma unroll
    for (int kt = 0; kt < 4; ++kt)
        a[kt] = *(const short8*)&A[r0 + m][kt * 32 + quad * 8];
    f32x4 acc[8];
    #pragma unroll
    for (int ct = 0; ct < 8; ++ct) acc[ct] = (f32x4){0.f, 0.f, 0.f, 0.f};
    short8 bcur[4], bnxt[4];
    {
        const unsigned short* wb = &wt1[(size_t)m * 128 + quad * 8];
        #pragma unroll
        for (int kt = 0; kt < 4; ++kt) bcur[kt] = *(const short8*)(wb + kt * 32);
    }
    #pragma unroll
    for (int ct = 0; ct < 8; ++ct) {
        if (ct < 7) {
            const unsigned short* wb = &wt1[(size_t)((ct + 1) * 16 + m) * 128 + quad * 8];
            #pragma unroll
            for (int kt = 0; kt < 4; ++kt) bnxt[kt] = *(const short8*)(wb + kt * 32);
        }
        #pragma unroll
        for (int kt = 0; kt < 4; ++kt)
            acc[ct] = __builtin_amdgcn_mfma_f32_16x16x32_bf16(a[kt], bcur[kt], acc[ct], 0, 0, 0);
        #pragma unroll
        for (int kt = 0; kt < 4; ++kt) bcur[kt] = bnxt[kt];
    }
    __syncthreads();
    #pragma unroll
    for (int ct = 0; ct < 8; ++ct) {
        int col = ct * 16 + m;
        #pragma unroll
        for (int reg = 0; reg < 4; ++reg)
            A[r0 + quad * 4 + reg][col] = bf16_1(acc[ct][reg]);
    }
    __syncthreads();
    #pragma unroll
    for (int i = 0; i < 4; ++i) {
        int idx = t + i * 256;
        int r = idx >> 4;
        int c8 = (idx & 15) * 8;
        int grow = row0 + r;
        if (grow < n)
            *(uint4*)&zb[(size_t)grow * 128 + c8] = *(const uint4*)&A[r][c8];
    }
}

// Phase 1: blocks [0,DB) edge-tile histograms; blocks [DB,..) gemm1 rows A.
__global__ __launch_bounds__(256) void k_hist_gemm1(const int* __restrict__ dst,
                                                    int* __restrict__ hist,
                                                    const float* __restrict__ x,
                                                    const unsigned short* __restrict__ wt1,
                                                    unsigned short* __restrict__ zb,
                                                    int E, int n, int DB) {
    __shared__ __align__(16) char smem[64 * ASTR * 2];
    int t = threadIdx.x;
    int b = blockIdx.x;
    if (b >= DB) {
        gemm1_tile(smem, (b - DB) * 64, x, wt1, zb, n, t);
        return;
    }
    int* h = (int*)smem;
    h[t] = 0;
    __syncthreads();
    int base = b * ETILE;
    #pragma unroll
    for (int i = 0; i < EPT; ++i) {
        int e = base + i * 256 + t;
        if (e < E) atomicAdd(&h[dst[e] >> 8], 1);
    }
    __syncthreads();
    hist[t * DB + b] = h[t];
}

// Phase 2: block k scans hist[k][0..DB) -> absolute off[k][b] (= k*CAP + prefix),
// bucket total -> bcurP[k*16]. DB <= 512.
__global__ __launch_bounds__(256) void k_scan(const int* __restrict__ hist,
                                              int* __restrict__ off,
                                              int* __restrict__ bcurP, int DB) {
    __shared__ int sc[512];
    int k = blockIdx.x, t = threadIdx.x;
    int v0 = (t < DB) ? hist[k * DB + t] : 0;
    int v1 = (256 + t < DB) ? hist[k * DB + 256 + t] : 0;
    sc[t] = v0;
    sc[256 + t] = v1;
    __syncthreads();
    for (int o = 1; o < 256; o <<= 1) {
        int a = (t >= o) ? sc[t - o] : 0;
        __syncthreads();
        sc[t] += a;
        __syncthreads();
    }
    for (int o = 1; o < 256; o <<= 1) {
        int a = (t >= o) ? sc[256 + t - o] : 0;
        __syncthreads();
        sc[256 + t] += a;
        __syncthreads();
    }
    int add = sc[255];
    sc[256 + t] += add;
    __syncthreads();
    int base = k * CAP;
    if (t < DB) off[k * DB + t] = base + sc[t] - v0;
    if (256 + t < DB) off[k * DB + 256 + t] = base + sc[256 + t] - v1;
    if (t == 0) bcurP[k * 16] = sc[511];
}

// Phase 3: blocks [0,DB) LDS counting sort + coalesced flush at precomputed
// offsets (NO atomics); blocks [DB,..) gemm1 rows B.
struct SmemDist {
    int h[NBKT], sx[NBKT], cur[NBKT], gb[NBKT];
    unsigned stage[ETILE];
};

__global__ __launch_bounds__(256) void k_scatter_gemm1(const int* __restrict__ src,
                                                       const int* __restrict__ dst,
                                                       const int* __restrict__ off,
                                                       unsigned* __restrict__ bpacked,
                                                       const float* __restrict__ x,
                                                       const unsigned short* __restrict__ wt1,
                                                       unsigned short* __restrict__ zb,
                                                       int E, int n, int DB, int row0B) {
    __shared__ __align__(16) char smem[sizeof(SmemDist)];
    int t = threadIdx.x;
    int b = blockIdx.x;
    if (b >= DB) {
        gemm1_tile(smem, row0B + (b - DB) * 64, x, wt1, zb, n, t);
        return;
    }
    SmemDist* s = (SmemDist*)smem;
    int mygb = off[t * DB + b];      // issue first: oldest in flight, retires free
    s->h[t] = 0;
    __syncthreads();
    int base = b * ETILE;
    int dreg[EPT];
    #pragma unroll
    for (int i = 0; i < EPT; ++i) {
        int e = base + i * 256 + t;
        dreg[i] = (e < E) ? dst[e] : -1;
        if (dreg[i] >= 0) atomicAdd(&s->h[dreg[i] >> 8], 1);
    }
    __syncthreads();
    int c = s->h[t];
    s->sx[t] = c;
    __syncthreads();
    for (int o = 1; o < NBKT; o <<= 1) {
        int v = (t >= o) ? s->sx[t - o] : 0;
        __syncthreads();
        s->sx[t] += v;
        __syncthreads();
    }
    int nvalid = s->sx[NBKT - 1];
    int excl = s->sx[t] - c;
    __syncthreads();
    s->sx[t] = excl;
    s->cur[t] = excl;
    s->gb[t] = mygb;                 // absolute segment base from scan
    __syncthreads();
    #pragma unroll
    for (int i = 0; i < EPT; ++i) {
        int e = base + i * 256 + t;
        if (dreg[i] >= 0) {
            int d = dreg[i];
            int bkt = d >> 8;
            int p = atomicAdd(&s->cur[bkt], 1);
            s->stage[p] = ((unsigned)d << 16) | (unsigned)src[e];
        }
    }
    __syncthreads();
    for (int idx = t; idx < nvalid; idx += 256) {
        unsigned v = s->stage[idx];
        int bkt = (int)(v >> 24);
        bpacked[s->gb[bkt] + (idx - s->sx[bkt])] = v;
    }
}

// bucket CSR counting sort (ushort col16, LDS-staged coalesced writes) +
// fused zb pre-scale by rsqrt(deg+1) for this bucket's own nodes.
struct SmemCSR {
    int cnt[NBKT], sA[NBKT], cur[NBKT];
    float disL[NBKT];
    unsigned short stage[CAP];
};

__global__ __launch_bounds__(256) void k_csr_scale(const unsigned* __restrict__ bpacked,
                                                   const int* __restrict__ bcurP,
                                                   int* __restrict__ row_ptr,
                                                   int* __restrict__ degA,
                                                   float* __restrict__ dis,
                                                   unsigned short* __restrict__ col16,
                                                   unsigned short* __restrict__ zb,
                                                   int n) {
    __shared__ __align__(16) char smemc[sizeof(SmemCSR)];
    SmemCSR* s = (SmemCSR*)smemc;
    int t = threadIdx.x;
    int b = blockIdx.x;
    int node0 = b << 8;
    int nn = n - node0;
    if (nn > 256) nn = 256;
    if (nn < 0) nn = 0;
    int e0 = b * CAP;
    int ne = bcurP[b * 16];
    s->cnt[t] = 0;
    __syncthreads();
    int n4 = (ne + 3) >> 2;
    for (int i = t; i < n4; i += 256) {
        uint4 v = *(const uint4*)&bpacked[e0 + 4 * i];
        int rem = ne - 4 * i;
        if (rem > 0) atomicAdd(&s->cnt[(v.x >> 16) & 255u], 1);
        if (rem > 1) atomicAdd(&s->cnt[(v.y >> 16) & 255u], 1);
        if (rem > 2) atomicAdd(&s->cnt[(v.z >> 16) & 255u], 1);
        if (rem > 3) atomicAdd(&s->cnt[(v.w >> 16) & 255u], 1);
    }
    __syncthreads();
    int c = s->cnt[t];
    s->sA[t] = c;
    __syncthreads();
    for (int o = 1; o < NBKT; o <<= 1) {
        int v = (t >= o) ? s->sA[t - o] : 0;
        __syncthreads();
        s->sA[t] += v;
        __syncthreads();
    }
    int excl = s->sA[t] - c;
    s->cur[t] = excl;
    float dv = rsqrtf((float)(c + 1));
    s->disL[t] = dv;
    if (t < nn) {
        row_ptr[node0 + t] = e0 + excl;
        degA[node0 + t] = c;
        dis[node0 + t] = dv;
    }
    __syncthreads();
    for (int i = t; i < n4; i += 256) {
        uint4 v = *(const uint4*)&bpacked[e0 + 4 * i];
        int rem = ne - 4 * i;
        unsigned vv[4] = {v.x, v.y, v.z, v.w};
        #pragma unroll
        for (int j = 0; j < 4; ++j) {
            if (rem > j) {
                int ld = (int)((vv[j] >> 16) & 255u);
                int p = atomicAdd(&s->cur[ld], 1);
                s->stage[p] = (unsigned short)(vv[j] & 0xFFFFu);
            }
        }
    }
    __syncthreads();
    // coalesced flush of the whole bucket segment (2 ushort per uint store)
    int nw = (ne + 1) >> 1;
    for (int i = t; i < nw; i += 256) {
        unsigned w = (unsigned)s->stage[2 * i] | ((unsigned)s->stage[2 * i + 1] << 16);
        *(unsigned*)&col16[e0 + 2 * i] = w;
    }
    // fused pre-scale of zb rows owned by this bucket
    for (int idx = t; idx < nn * 16; idx += 256) {
        int r = idx >> 4;
        int c8 = (idx & 15) * 8;
        float sc = s->disL[r];
        size_t o8 = (size_t)(node0 + r) * 128 + c8;
        uint4 v = *(const uint4*)&zb[o8];
        unsigned* w = (unsigned*)&v;
        #pragma unroll
        for (int k2 = 0; k2 < 4; ++k2) {
            float2 f = unpack_bf2(w[k2]);
            w[k2] = pack_bf2(f.x * sc, f.y * sc);
        }
        *(uint4*)&zb[o8] = v;
    }
}

// =============== gather core: 16 lanes/node, 8-edge tiles, shuffle indices ===============
// Round-4 proven form: 2 row buffers (vA/vB), ushort indices distributed across
// the part's 16 lanes (c0,c1 = 32 edges; n0,n1 prefetched a macro ahead),
// pulled with __shfl at issue time. Every s_waitcnt is counted. VGPR ~84 ->
// 6 waves/SIMD; deeper pipelines trade occupancy 1:1 and don't help (R5).

__device__ __forceinline__ void gather_pipe(const unsigned short* __restrict__ hws,
                                            const unsigned short* __restrict__ col16,
                                            int e0, int deg, int md, int sl, int part,
                                            float* acc8) {
    int nt = (md + 7) >> 3;
    if (nt <= 0) return;
    int base = part << 4;
    uint4 vA[8], vB[8];
    int c0, c1, n0 = 0, n1 = 0;
    c0 = (sl < deg) ? (int)col16[e0 + sl] : 0;
    c1 = (sl + 16 < deg) ? (int)col16[e0 + 16 + sl] : 0;

    // issue tile 0 -> vA
    #pragma unroll
    for (int j = 0; j < 8; ++j) {
        int s = __shfl(c0, base + j);
        vA[j] = (j < deg) ? *(const uint4*)(hws + ((size_t)s << 7) + (sl << 3))
                          : make_uint4(0, 0, 0, 0);
    }
    int t = 0, ebase = 0;
    for (;;) {
        // ---- phase0: tile t (==0 mod 4) in vA ----
        if (t + 4 < nt) {   // prefetch next macro's indices FIRST (oldest for counted wait)
            n0 = (ebase + 32 + sl < deg) ? (int)col16[e0 + ebase + 32 + sl] : 0;
            n1 = (ebase + 48 + sl < deg) ? (int)col16[e0 + ebase + 48 + sl] : 0;
        }
        if (t + 1 < nt) {
            int it0 = (t + 1) << 3;
            #pragma unroll
            for (int j = 0; j < 8; ++j) {
                int s = __shfl(c0, base + 8 + j);
                vB[j] = (it0 + j < deg) ? *(const uint4*)(hws + ((size_t)s << 7) + (sl << 3))
                                        : make_uint4(0, 0, 0, 0);
            }
        }
        #pragma unroll
        for (int j = 0; j < 8; ++j) {
            const unsigned* w = (const unsigned*)&vA[j];
            #pragma unroll
            for (int i2 = 0; i2 < 4; ++i2) {
                float2 f = unpack_bf2(w[i2]);
                acc8[2 * i2]     += f.x;
                acc8[2 * i2 + 1] += f.y;
            }
        }
        if (++t >= nt) break;
        // ---- phase1: tile t in vB ----
        if (t + 1 < nt) {
            int it0 = (t + 1) << 3;
            #pragma unroll
            for (int j = 0; j < 8; ++j) {
                int s = __shfl(c1, base + j);
                vA[j] = (it0 + j < deg) ? *(const uint4*)(hws + ((size_t)s << 7) + (sl << 3))
                                        : make_uint4(0, 0, 0, 0);
            }
        }
        #pragma unroll
        for (int j = 0; j < 8; ++j) {
            const unsigned* w = (const unsigned*)&vB[j];
            #pragma unroll
            for (int i2 = 0; i2 < 4; ++i2) {
                float2 f = unpack_bf2(w[i2]);
                acc8[2 * i2]     += f.x;
                acc8[2 * i2 + 1] += f.y;
            }
        }
        if (++t >= nt) break;
        // ---- phase2: tile t in vA ----
        if (t + 1 < nt) {
            int it0 = (t + 1) << 3;
            #pragma unroll
            for (int j = 0; j < 8; ++j) {
                int s = __shfl(c1, base + 8 + j);
                vB[j] = (it0 + j < deg) ? *(const uint4*)(hws + ((size_t)s << 7) + (sl << 3))
                                        : make_uint4(0, 0, 0, 0);
            }
        }
        #pragma unroll
        for (int j = 0; j < 8; ++j) {
            const unsigned* w = (const unsigned*)&vA[j];
            #pragma unroll
            for (int i2 = 0; i2 < 4; ++i2) {
                float2 f = unpack_bf2(w[i2]);
                acc8[2 * i2]     += f.x;
                acc8[2 * i2 + 1] += f.y;
            }
        }
        if (++t >= nt) break;
        // ---- phase3: tile t in vB; next tile uses the prefetched n0 ----
        if (t + 1 < nt) {
            int it0 = (t + 1) << 3;
            #pragma unroll
            for (int j = 0; j < 8; ++j) {
                int s = __shfl(n0, base + j);
                vA[j] = (it0 + j < deg) ? *(const uint4*)(hws + ((size_t)s << 7) + (sl << 3))
                                        : make_uint4(0, 0, 0, 0);
            }
        }
        #pragma unroll
        for (int j = 0; j < 8; ++j) {
            const unsigned* w = (const unsigned*)&vB[j];
            #pragma unroll
            for (int i2 = 0; i2 < 4; ++i2) {
                float2 f = unpack_bf2(w[i2]);
                acc8[2 * i2]     += f.x;
                acc8[2 * i2 + 1] += f.y;
            }
        }
        if (++t >= nt) break;
        c0 = n0; c1 = n1; ebase += 32;
    }
}

// ------- FUSED: layer-1 agg (unscaled gather of pre-scaled zb) + BN + ReLU
//         -> h1 (LDS) -> GEMM2 -> hws2 (pre-scaled) -------

__global__ __launch_bounds__(256, 3) void k_agg1_gemm2(const unsigned short* __restrict__ zb,
                                                       const int* __restrict__ row_ptr,
                                                       const int* __restrict__ degA,
                                                       const unsigned short* __restrict__ col16,
                                                       const float* __restrict__ dis,
                                                       const float* __restrict__ bias,
                                                       const float* __restrict__ gamma,
                                                       const float* __restrict__ beta,
                                                       const float* __restrict__ mean,
                                                       const float* __restrict__ var,
                                                       const unsigned short* __restrict__ wt2,
                                                       unsigned short* __restrict__ hwsb2, int n) {
    __shared__ unsigned short H1[16][ASTR];
    __shared__ unsigned short C2[16][ASTR];
    int t = threadIdx.x;
    int wave = t >> 6, lane = t & 63;
    int sl = lane & 15, part = lane >> 4;
    int d = blockIdx.x * 16 + wave * 4 + part;
    bool active = (d < n);
    int e0 = 0, deg = 0;
    if (active) {
        e0 = row_ptr[d];
        deg = degA[d];
    }
    // preload self row + self dis BEFORE the gather: oldest in flight, retire free
    uint4 vs = make_uint4(0, 0, 0, 0);
    float dd = 0.f;
    if (active) {
        vs = *(const uint4*)(zb + ((size_t)d << 7) + (sl << 3));
        dd = dis[d];
    }
    int md = deg;
    md = max(md, __shfl_xor(md, 16));
    md = max(md, __shfl_xor(md, 32));

    float acc8[8] = {0, 0, 0, 0, 0, 0, 0, 0};
    gather_pipe(zb, col16, e0, deg, md, sl, part, acc8);

    unsigned outw[4] = {0, 0, 0, 0};
    if (active) {
        const unsigned* w = (const unsigned*)&vs;
        #pragma unroll
        for (int i2 = 0; i2 < 4; ++i2) {
            float2 f = unpack_bf2(w[i2]);
            acc8[2 * i2]     += f.x;   // zb pre-scaled: self term is zs[d]
            acc8[2 * i2 + 1] += f.y;
        }
        int f0 = sl << 3;
        #pragma unroll
        for (int i2 = 0; i2 < 4; ++i2) {
            int f = f0 + 2 * i2;
            float2 bv = *(const float2*)&bias[f];
            float2 gm = *(const float2*)&gamma[f];
            float2 bt = *(const float2*)&beta[f];
            float2 mn = *(const float2*)&mean[f];
            float2 vr = *(const float2*)&var[f];
            float vx = acc8[2 * i2] * dd + bv.x;
            float vy = acc8[2 * i2 + 1] * dd + bv.y;
            float sx = gm.x * rsqrtf(vr.x + BN_EPS);
            float sy = gm.y * rsqrtf(vr.y + BN_EPS);
            float rx = fmaxf((vx - mn.x) * sx + bt.x, 0.f);
            float ry = fmaxf((vy - mn.y) * sy + bt.y, 0.f);
            outw[i2] = pack_bf2(rx, ry);
        }
    }
    int local = wave * 4 + part;
    *(uint4*)&H1[local][sl << 3] = *(uint4*)outw;
    __syncthreads();

    int m = sl;
    int quad = part;
    short8 a2[4];
    #pragma unroll
    for (int kt = 0; kt < 4; ++kt)
        a2[kt] = *(const short8*)&H1[m][kt * 32 + quad * 8];

    f32x4 acc2[2];
    acc2[0] = (f32x4){0.f, 0.f, 0.f, 0.f};
    acc2[1] = (f32x4){0.f, 0.f, 0.f, 0.f};
    #pragma unroll
    for (int i = 0; i < 2; ++i) {
        int ct = wave * 2 + i;
        const unsigned short* wb = &wt2[(size_t)(ct * 16 + m) * 128 + quad * 8];
        #pragma unroll
        for (int kt = 0; kt < 4; ++kt) {
            short8 b = *(const short8*)(wb + kt * 32);
            acc2[i] = __builtin_amdgcn_mfma_f32_16x16x32_bf16(a2[kt], b, acc2[i], 0, 0, 0);
        }
    }
    int gr = blockIdx.x * 16 + quad * 4;
    float ds2[4];
    #pragma unroll
    for (int reg = 0; reg < 4; ++reg)
        ds2[reg] = (gr + reg < n) ? dis[gr + reg] : 0.f;
    #pragma unroll
    for (int i = 0; i < 2; ++i) {
        int col = (wave * 2 + i) * 16 + m;
        #pragma unroll
        for (int reg = 0; reg < 4; ++reg)
            C2[quad * 4 + reg][col] = bf16_1(acc2[i][reg] * ds2[reg]);
    }
    __syncthreads();
    {
        int r = t >> 4;
        int c8 = (t & 15) * 8;
        int grow = blockIdx.x * 16 + r;
        if (grow < n)
            *(uint4*)&hwsb2[(size_t)grow * 128 + c8] = *(const uint4*)&C2[r][c8];
    }
}

// ------- layer-2 agg + BN + ReLU + attention + logits; block=256, 16 nodes -------

__global__ __launch_bounds__(256, 3) void k_agg2_att_logit(const unsigned short* __restrict__ hwsb,
                                                           const int* __restrict__ row_ptr,
                                                           const int* __restrict__ degA,
                                                           const unsigned short* __restrict__ col16,
                                                           const float* __restrict__ dis,
                                                           const float* __restrict__ bias,
                                                           const float* __restrict__ gamma,
                                                           const float* __restrict__ beta,
                                                           const float* __restrict__ mean,
                                                           const float* __restrict__ var,
                                                           const int* __restrict__ batch,
                                                           const float* __restrict__ att_w,
                                                           const float* __restrict__ cls_w,
                                                           float* __restrict__ att_out,
                                                           float* __restrict__ logits, int n) {
    __shared__ int   sg[16];
    __shared__ float sv[16];
    int t = threadIdx.x;
    int wave = t >> 6, lane = t & 63;
    int sl = lane & 15, part = lane >> 4;
    int d = blockIdx.x * 16 + wave * 4 + part;
    bool active = (d < n);
    int e0 = 0, deg = 0;
    if (active) {
        e0 = row_ptr[d];
        deg = degA[d];
    }
    // preload self row, self dis, and batch id BEFORE the gather
    uint4 vs = make_uint4(0, 0, 0, 0);
    float dd = 0.f;
    int g = -1;
    if (active) {
        vs = *(const uint4*)(hwsb + ((size_t)d << 7) + (sl << 3));
        dd = dis[d];
        g = batch[d];
    }
    int md = deg;
    md = max(md, __shfl_xor(md, 16));
    md = max(md, __shfl_xor(md, 32));

    float acc8[8] = {0, 0, 0, 0, 0, 0, 0, 0};
    gather_pipe(hwsb, col16, e0, deg, md, sl, part, acc8);

    float contrib = 0.f;
    float p = 0.f, q = 0.f;
    if (active) {
        const unsigned* w = (const unsigned*)&vs;
        #pragma unroll
        for (int i2 = 0; i2 < 4; ++i2) {
            float2 f = unpack_bf2(w[i2]);
            acc8[2 * i2]     += f.x;
            acc8[2 * i2 + 1] += f.y;
        }
        int f0 = sl << 3;
        #pragma unroll
        for (int i2 = 0; i2 < 4; ++i2) {
            int f = f0 + 2 * i2;
            float2 bv = *(const float2*)&bias[f];
            float2 gm = *(const float2*)&gamma[f];
            float2 bt = *(const float2*)&beta[f];
            float2 mn = *(const float2*)&mean[f];
            float2 vr = *(const float2*)&var[f];
            float vx = acc8[2 * i2] * dd + bv.x;
            float vy = acc8[2 * i2 + 1] * dd + bv.y;
            float sx = gm.x * rsqrtf(vr.x + BN_EPS);
            float sy = gm.y * rsqrtf(vr.y + BN_EPS);
            float rx = fmaxf((vx - mn.x) * sx + bt.x, 0.f);
            float ry = fmaxf((vy - mn.y) * sy + bt.y, 0.f);
            float2 aw = *(const float2*)&att_w[f];
            float2 cw = *(const float2*)&cls_w[f];
            p += rx * aw.x + ry * aw.y;
            q += rx * cw.x + ry * cw.y;
        }
    }
    #pragma unroll
    for (int off = 1; off < 16; off <<= 1) {
        p += __shfl_xor(p, off);
        q += __shfl_xor(q, off);
    }
    if (active) {
        float a = 1.f / (1.f + expf(-p));
        if (sl == 0) att_out[d] = a;
        contrib = a * q;
    }
    if (sl == 0) {
        sg[wave * 4 + part] = g;
        sv[wave * 4 + part] = contrib;
    }
    __syncthreads();
    if (t == 0) {
        int cur = -1;
        float acc = 0.f;
        #pragma unroll
        for (int i = 0; i < 16; ++i) {
            int gi = sg[i];
            if (gi < 0) continue;
            if (gi != cur) {
                if (cur >= 0) atomicAdd(&logits[cur], acc);
                cur = gi;
                acc = 0.f;
            }
            acc += sv[i];
        }
        if (cur >= 0) atomicAdd(&logits[cur], acc);
    }
}

// ---------------- launch ----------------

extern "C" void kernel_launch(void* const* d_in, const int* in_sizes, int n_in,
                              void* d_out, int out_size, void* d_ws, size_t ws_size,
                              hipStream_t stream) {
    const float* x   = (const float*)d_in[0];
    const int*   ei  = (const int*)d_in[1];
    const int*   bat = (const int*)d_in[2];
    const float* W1  = (const float*)d_in[3];
    const float* b1  = (const float*)d_in[4];
    const float* g1  = (const float*)d_in[5];
    const float* bt1 = (const float*)d_in[6];
    const float* mn1 = (const float*)d_in[7];
    const float* vr1 = (const float*)d_in[8];
    const float* W2  = (const float*)d_in[9];
    const float* b2  = (const float*)d_in[10];
    const float* g2  = (const float*)d_in[11];
    const float* bt2 = (const float*)d_in[12];
    const float* mn2 = (const float*)d_in[13];
    const float* vr2 = (const float*)d_in[14];
    const float* attw = (const float*)d_in[15];
    const float* clsw = (const float*)d_in[16];
    const float* clsb = (const float*)d_in[17];

    int E = in_sizes[1] / 2;
    int n = in_sizes[2];
    const int* src = ei;
    const int* dst = ei + E;
    int NB = (n + 255) >> 8;       // buckets of 256 nodes

    char* ws = (char*)d_ws;
    auto alloc = [&](size_t bytes) {
        void* p = (void*)ws;
        ws += (bytes + 255) & ~(size_t)255;
        return p;
    };
    int DB = (E + ETILE - 1) / ETILE;   // <= 512 (scan kernel assumption)

    int*            bcurP   = (int*)alloc(NBKT * 16 * 4);
    unsigned*       bpacked = (unsigned*)alloc((size_t)NBKT * CAP * 4);
    int*            row_ptr = (int*)alloc((size_t)n * 4);
    int*            degA    = (int*)alloc((size_t)n * 4);
    unsigned short* col16   = (unsigned short*)alloc(((size_t)NBKT * CAP + 1024) * 2);
    float*          dis     = (float*)alloc((size_t)n * 4);
    unsigned short* zb      = (unsigned short*)alloc((size_t)n * 128 * 2);
    unsigned short* hwsb2   = (unsigned short*)alloc((size_t)n * 128 * 2);
    unsigned short* wt1     = (unsigned short*)alloc(128 * 128 * 2);
    unsigned short* wt2     = (unsigned short*)alloc(128 * 128 * 2);
    int*            hist    = (int*)alloc((size_t)NBKT * DB * 4);
    int*            offs    = (int*)alloc((size_t)NBKT * DB * 4);

    float* out = (float*)d_out;
    int gb = (n + 63) / 64;
    int G1A = gb / 2;              // gemm1 rows [0, G1A*64) with hist
    int G1B = gb - G1A;            // remaining rows with scatter
    int ab = (n + 15) / 16;

    k_prep0<<<257, 128, 0, stream>>>(W1, W2, wt1, wt2, clsb, out);
    k_hist_gemm1<<<DB + G1A, 256, 0, stream>>>(dst, hist, x, wt1, zb, E, n, DB);
    k_scan<<<NBKT, 256, 0, stream>>>(hist, offs, bcurP, DB);
    k_scatter_gemm1<<<DB + G1B, 256, 0, stream>>>(src, dst, offs, bpacked, x, wt1, zb,
                                                  E, n, DB, G1A * 64);
    k_csr_scale<<<NB, 256, 0, stream>>>(bpacked, bcurP, row_ptr, degA, dis,
                                        col16, zb, n);
    k_agg1_gemm2<<<ab, 256, 0, stream>>>(zb, row_ptr, degA, col16, dis,
                                         b1, g1, bt1, mn1, vr1, wt2, hwsb2, n);
    k_agg2_att_logit<<<ab, 256, 0, stream>>>(hwsb2, row_ptr, degA, col16, dis,
                                             b2, g2, bt2, mn2, vr2, bat, attw, clsw,
                                             out + NG, out, n);
}

// Round 10
// 256.908 us; speedup vs baseline: 1.0623x; 1.0623x over previous
//
#include <hip/hip_runtime.h>
#include <math.h>

#define NN 50000
#define HID 128
#define NG 64
#define BN_EPS 1e-5f

typedef __attribute__((ext_vector_type(8))) short short8;
typedef __attribute__((ext_vector_type(4))) float f32x4;
typedef __attribute__((ext_vector_type(2))) float f32x2;

// ---- bf16 pack/unpack (RNE) ----
__device__ inline unsigned pack_bf2(float a, float b) {
    union { float f; unsigned u; } ua, ub;
    ua.f = a; ub.f = b;
    unsigned x = ua.u, y = ub.u;
    x += 0x7fffu + ((x >> 16) & 1u);
    y += 0x7fffu + ((y >> 16) & 1u);
    return (x >> 16) | (y & 0xffff0000u);
}
__device__ inline unsigned short bf16_1(float x) {
    union { float f; unsigned u; } v;
    v.f = x;
    unsigned r = v.u + 0x7fffu + ((v.u >> 16) & 1u);
    return (unsigned short)(r >> 16);
}
__device__ inline float2 unpack_bf2(unsigned v) {
    union { unsigned u; float f; } a, b;
    a.u = v << 16;
    b.u = v & 0xffff0000u;
    return make_float2(a.f, b.f);
}
// bf16-pair -> f32x2 (for packed v_pk_add_f32 accumulation)
__device__ __forceinline__ f32x2 bf2_to_f32x2(unsigned u) {
    union { unsigned q; float f; } a, b;
    a.q = u << 16;
    b.q = u & 0xffff0000u;
    f32x2 r;
    r.x = a.f;
    r.y = b.f;
    return r;
}

// =============== CSR build — fixed-capacity buckets ===============
// K = 256 nodes/bucket (pow2: bkt = d>>8, ld = d&255 — no int division).
// R9 lesson: radix (no-atomic) build was neutral-negative; R8's atomic-cursor
// split-fused form is the measured best — kept verbatim.
#define NBKT 256                 // scan width (buckets used = NB <= 256)
#define ETILE 4096
#define EPT   (ETILE / 256)      // 16 edges per thread
#define CAP   10240              // avg bucket load 8192; +25% headroom
#define ASTR 136

// prep: blocks 0..255 W transpose+bf16; block 256 zero cursors + seed logits
__global__ __launch_bounds__(128) void k_prep0(const float* __restrict__ W1,
                                               const float* __restrict__ W2,
                                               unsigned short* __restrict__ wt1,
                                               unsigned short* __restrict__ wt2,
                                               int* __restrict__ bcurP,
                                               const float* __restrict__ cls_b,
                                               float* __restrict__ logits) {
    int b = blockIdx.x;
    int t = threadIdx.x;
    if (b < 256) {
        int k = b & 127;
        const float* W = (b < 128) ? W1 : W2;
        unsigned short* wt = (b < 128) ? wt1 : wt2;
        wt[t * 128 + k] = bf16_1(W[k * 128 + t]);
    } else {
        #pragma unroll
        for (int i = 0; i < 32; ++i) bcurP[t * 32 + i] = 0;
        if (t < NG) logits[t] = cls_b[0];
    }
}

// ---- shared gemm1 tile body: z[row0..row0+64) = bf16(x@W1), UNSCALED ----
__device__ __forceinline__ void gemm1_tile(char* smem, int row0,
                                           const float* __restrict__ x,
                                           const unsigned short* __restrict__ wt1,
                                           unsigned short* __restrict__ zb,
                                           int n, int t) {
    typedef unsigned short ArowT[ASTR];
    ArowT* A = (ArowT*)smem;
    #pragma unroll
    for (int i = 0; i < 8; ++i) {
        int idx = t + i * 256;
        int r = idx >> 5;
        int c4 = (idx & 31) * 4;
        float4 v = make_float4(0.f, 0.f, 0.f, 0.f);
        if (row0 + r < n) v = *(const float4*)&x[(size_t)(row0 + r) * 128 + c4];
        uint2 p;
        p.x = pack_bf2(v.x, v.y);
        p.y = pack_bf2(v.z, v.w);
        *(uint2*)&A[r][c4] = p;
    }
    __syncthreads();
    int lane = t & 63;
    int wave = t >> 6;
    int m = lane & 15;
    int quad = lane >> 4;
    int r0 = wave * 16;
    short8 a[4];
    #pragma unroll
    for (int kt = 0; kt < 4; ++kt)
        a[kt] = *(const short8*)&A[r0 + m][kt * 32 + quad * 8];
    f32x4 acc[8];
    #pragma unroll
    for (int ct = 0; ct < 8; ++ct) acc[ct] = (f32x4){0.f, 0.f, 0.f, 0.f};
    short8 bcur[4], bnxt[4];
    {
        const unsigned short* wb = &wt1[(size_t)m * 128 + quad * 8];
        #pragma unroll
        for (int kt = 0; kt < 4; ++kt) bcur[kt] = *(const short8*)(wb + kt * 32);
    }
    #pragma unroll
    for (int ct = 0; ct < 8; ++ct) {
        if (ct < 7) {
            const unsigned short* wb = &wt1[(size_t)((ct + 1) * 16 + m) * 128 + quad * 8];
            #pragma unroll
            for (int kt = 0; kt < 4; ++kt) bnxt[kt] = *(const short8*)(wb + kt * 32);
        }
        #pragma unroll
        for (int kt = 0; kt < 4; ++kt)
            acc[ct] = __builtin_amdgcn_mfma_f32_16x16x32_bf16(a[kt], bcur[kt], acc[ct], 0, 0, 0);
        #pragma unroll
        for (int kt = 0; kt < 4; ++kt) bcur[kt] = bnxt[kt];
    }
    __syncthreads();
    #pragma unroll
    for (int ct = 0; ct < 8; ++ct) {
        int col = ct * 16 + m;
        #pragma unroll
        for (int reg = 0; reg < 4; ++reg)
            A[r0 + quad * 4 + reg][col] = bf16_1(acc[ct][reg]);
    }
    __syncthreads();
    #pragma unroll
    for (int i = 0; i < 4; ++i) {
        int idx = t + i * 256;
        int r = idx >> 4;
        int c8 = (idx & 15) * 8;
        int grow = row0 + r;
        if (grow < n)
            *(uint4*)&zb[(size_t)grow * 128 + c8] = *(const uint4*)&A[r][c8];
    }
}

// L2a: blocks [0,DB) = edge distribute (coalesced LDS counting sort);
//      blocks [DB,..) = gemm1 rows [0, G1A*64).
struct SmemDist {
    int h[NBKT], sx[NBKT], cur[NBKT], gb[NBKT];
    unsigned stage[ETILE];
};

__global__ __launch_bounds__(256) void k_dist_gemm1(const int* __restrict__ src,
                                                    const int* __restrict__ dst,
                                                    int* __restrict__ bcurP,
                                                    unsigned* __restrict__ bpacked,
                                                    const float* __restrict__ x,
                                                    const unsigned short* __restrict__ wt1,
                                                    unsigned short* __restrict__ zb,
                                                    int E, int n, int DB) {
    __shared__ __align__(16) char smem[sizeof(SmemDist)];
    int t = threadIdx.x;
    int b = blockIdx.x;

    if (b >= DB) {
        gemm1_tile(smem, (b - DB) * 64, x, wt1, zb, n, t);
        return;
    }
    // ---------------- distribute path ----------------
    SmemDist* s = (SmemDist*)smem;
    s->h[t] = 0;
    __syncthreads();
    int base = b * ETILE;
    int dreg[EPT];
    #pragma unroll
    for (int i = 0; i < EPT; ++i) {
        int e = base + i * 256 + t;
        dreg[i] = (e < E) ? dst[e] : -1;
        if (dreg[i] >= 0) atomicAdd(&s->h[dreg[i] >> 8], 1);
    }
    __syncthreads();
    int c = s->h[t];
    s->sx[t] = c;
    __syncthreads();
    for (int off = 1; off < NBKT; off <<= 1) {
        int v = (t >= off) ? s->sx[t - off] : 0;
        __syncthreads();
        s->sx[t] += v;
        __syncthreads();
    }
    int nvalid = s->sx[NBKT - 1];
    int excl = s->sx[t] - c;
    __syncthreads();
    s->sx[t] = excl;
    s->cur[t] = excl;
    s->gb[t] = (c > 0) ? atomicAdd(&bcurP[t * 16], c) : 0;
    __syncthreads();
    #pragma unroll
    for (int i = 0; i < EPT; ++i) {
        int e = base + i * 256 + t;
        if (dreg[i] >= 0) {
            int d = dreg[i];
            int bkt = d >> 8;
            int p = atomicAdd(&s->cur[bkt], 1);
            s->stage[p] = ((unsigned)d << 16) | (unsigned)src[e];
        }
    }
    __syncthreads();
    for (int idx = t; idx < nvalid; idx += 256) {
        unsigned v = s->stage[idx];
        int bkt = (int)(v >> 24);
        int pos = s->gb[bkt] + (idx - s->sx[bkt]);
        bpacked[(size_t)bkt * CAP + pos] = v;
    }
}

// L2b: blocks [0,NB) = bucket CSR counting sort (ushort col16, LDS-staged
//      coalesced writes); blocks [NB,..) = gemm1 rows [G1A*64, n).
struct SmemCSR {
    int cnt[NBKT], sA[NBKT], cur[NBKT];
    unsigned short stage[CAP];
};

__global__ __launch_bounds__(256) void k_csr_gemm1(const unsigned* __restrict__ bpacked,
                                                   const int* __restrict__ bcurP,
                                                   int* __restrict__ row_ptr,
                                                   int* __restrict__ degA,
                                                   float* __restrict__ dis,
                                                   unsigned short* __restrict__ col16,
                                                   const float* __restrict__ x,
                                                   const unsigned short* __restrict__ wt1,
                                                   unsigned short* __restrict__ zb,
                                                   int n, int NB, int row0B) {
    __shared__ __align__(16) char smem[sizeof(SmemCSR)];
    int t = threadIdx.x;
    int b = blockIdx.x;

    if (b >= NB) {
        gemm1_tile(smem, row0B + (b - NB) * 64, x, wt1, zb, n, t);
        return;
    }
    // ---------------- bucket CSR path ----------------
    SmemCSR* s = (SmemCSR*)smem;
    int node0 = b << 8;
    int nn = n - node0;
    if (nn > 256) nn = 256;
    if (nn < 0) nn = 0;
    int e0 = b * CAP;
    int ne = bcurP[b * 16];
    s->cnt[t] = 0;
    __syncthreads();
    int n4 = (ne + 3) >> 2;
    for (int i = t; i < n4; i += 256) {
        uint4 v = *(const uint4*)&bpacked[e0 + 4 * i];
        int rem = ne - 4 * i;
        if (rem > 0) atomicAdd(&s->cnt[(v.x >> 16) & 255u], 1);
        if (rem > 1) atomicAdd(&s->cnt[(v.y >> 16) & 255u], 1);
        if (rem > 2) atomicAdd(&s->cnt[(v.z >> 16) & 255u], 1);
        if (rem > 3) atomicAdd(&s->cnt[(v.w >> 16) & 255u], 1);
    }
    __syncthreads();
    int c = s->cnt[t];
    s->sA[t] = c;
    __syncthreads();
    for (int off = 1; off < NBKT; off <<= 1) {
        int v = (t >= off) ? s->sA[t - off] : 0;
        __syncthreads();
        s->sA[t] += v;
        __syncthreads();
    }
    int excl = s->sA[t] - c;
    s->cur[t] = excl;
    if (t < nn) {
        row_ptr[node0 + t] = e0 + excl;
        degA[node0 + t] = c;
        dis[node0 + t] = rsqrtf((float)(c + 1));
    }
    __syncthreads();
    for (int i = t; i < n4; i += 256) {
        uint4 v = *(const uint4*)&bpacked[e0 + 4 * i];
        int rem = ne - 4 * i;
        unsigned vv[4] = {v.x, v.y, v.z, v.w};
        #pragma unroll
        for (int j = 0; j < 4; ++j) {
            if (rem > j) {
                int ld = (int)((vv[j] >> 16) & 255u);
                int p = atomicAdd(&s->cur[ld], 1);
                s->stage[p] = (unsigned short)(vv[j] & 0xFFFFu);
            }
        }
    }
    __syncthreads();
    // coalesced flush of the whole bucket segment (2 ushort per uint store)
    int nw = (ne + 1) >> 1;
    for (int i = t; i < nw; i += 256) {
        unsigned w = (unsigned)s->stage[2 * i] | ((unsigned)s->stage[2 * i + 1] << 16);
        *(unsigned*)&col16[e0 + 2 * i] = w;
    }
}

// pre-scale zb rows by dis[row] (= rsqrt(deg+1)).
__global__ __launch_bounds__(256) void k_scale(unsigned short* __restrict__ zb,
                                               const float* __restrict__ dis, int n) {
    int i = blockIdx.x * 256 + threadIdx.x;
    int r = i >> 4;
    if (r >= n) return;
    int c8 = (i & 15) * 8;
    float s = dis[r];
    uint4 v = *(const uint4*)&zb[(size_t)r * 128 + c8];
    unsigned* w = (unsigned*)&v;
    #pragma unroll
    for (int k = 0; k < 4; ++k) {
        float2 f = unpack_bf2(w[k]);
        w[k] = pack_bf2(f.x * s, f.y * s);
    }
    *(uint4*)&zb[(size_t)r * 128 + c8] = v;
}

// =============== gather core: 16 lanes/node, 8-edge tiles, shuffle indices ===============
// Round-4 proven pipeline; consume now accumulates into f32x2 vectors so the
// 64 scalar v_add_f32 per tile become 32 v_pk_add_f32 (CDNA full-rate packed
// f32) — ~25% fewer VALU insts on the gather critical path.

__device__ __forceinline__ void consume8(const uint4* v, f32x2* acc) {
    #pragma unroll
    for (int j = 0; j < 8; ++j) {
        const unsigned* w = (const unsigned*)&v[j];
        #pragma unroll
        for (int i2 = 0; i2 < 4; ++i2)
            acc[i2] += bf2_to_f32x2(w[i2]);
    }
}

__device__ __forceinline__ void gather_pipe(const unsigned short* __restrict__ hws,
                                            const unsigned short* __restrict__ col16,
                                            int e0, int deg, int md, int sl, int part,
                                            f32x2* acc) {
    int nt = (md + 7) >> 3;
    if (nt <= 0) return;
    int base = part << 4;
    uint4 vA[8], vB[8];
    int c0, c1, n0 = 0, n1 = 0;
    c0 = (sl < deg) ? (int)col16[e0 + sl] : 0;
    c1 = (sl + 16 < deg) ? (int)col16[e0 + 16 + sl] : 0;

    // issue tile 0 -> vA
    #pragma unroll
    for (int j = 0; j < 8; ++j) {
        int s = __shfl(c0, base + j);
        vA[j] = (j < deg) ? *(const uint4*)(hws + ((size_t)s << 7) + (sl << 3))
                          : make_uint4(0, 0, 0, 0);
    }
    int t = 0, ebase = 0;
    for (;;) {
        // ---- phase0: tile t (==0 mod 4) in vA ----
        if (t + 4 < nt) {   // prefetch next macro's indices FIRST (oldest for counted wait)
            n0 = (ebase + 32 + sl < deg) ? (int)col16[e0 + ebase + 32 + sl] : 0;
            n1 = (ebase + 48 + sl < deg) ? (int)col16[e0 + ebase + 48 + sl] : 0;
        }
        if (t + 1 < nt) {
            int it0 = (t + 1) << 3;
            #pragma unroll
            for (int j = 0; j < 8; ++j) {
                int s = __shfl(c0, base + 8 + j);
                vB[j] = (it0 + j < deg) ? *(const uint4*)(hws + ((size_t)s << 7) + (sl << 3))
                                        : make_uint4(0, 0, 0, 0);
            }
        }
        consume8(vA, acc);
        if (++t >= nt) break;
        // ---- phase1: tile t in vB ----
        if (t + 1 < nt) {
            int it0 = (t + 1) << 3;
            #pragma unroll
            for (int j = 0; j < 8; ++j) {
                int s = __shfl(c1, base + j);
                vA[j] = (it0 + j < deg) ? *(const uint4*)(hws + ((size_t)s << 7) + (sl << 3))
                                        : make_uint4(0, 0, 0, 0);
            }
        }
        consume8(vB, acc);
        if (++t >= nt) break;
        // ---- phase2: tile t in vA ----
        if (t + 1 < nt) {
            int it0 = (t + 1) << 3;
            #pragma unroll
            for (int j = 0; j < 8; ++j) {
                int s = __shfl(c1, base + 8 + j);
                vB[j] = (it0 + j < deg) ? *(const uint4*)(hws + ((size_t)s << 7) + (sl << 3))
                                        : make_uint4(0, 0, 0, 0);
            }
        }
        consume8(vA, acc);
        if (++t >= nt) break;
        // ---- phase3: tile t in vB; next tile uses the prefetched n0 ----
        if (t + 1 < nt) {
            int it0 = (t + 1) << 3;
            #pragma unroll
            for (int j = 0; j < 8; ++j) {
                int s = __shfl(n0, base + j);
                vA[j] = (it0 + j < deg) ? *(const uint4*)(hws + ((size_t)s << 7) + (sl << 3))
                                        : make_uint4(0, 0, 0, 0);
            }
        }
        consume8(vB, acc);
        if (++t >= nt) break;
        c0 = n0; c1 = n1; ebase += 32;
    }
}

// ------- FUSED: layer-1 agg (unscaled gather of pre-scaled zb) + BN + ReLU
//         -> h1 (LDS) -> GEMM2 -> hws2 (pre-scaled) -------

__global__ __launch_bounds__(256, 3) void k_agg1_gemm2(const unsigned short* __restrict__ zb,
                                                       const int* __restrict__ row_ptr,
                                                       const int* __restrict__ degA,
                                                       const unsigned short* __restrict__ col16,
                                                       const float* __restrict__ dis,
                                                       const float* __restrict__ bias,
                                                       const float* __restrict__ gamma,
                                                       const float* __restrict__ beta,
                                                       const float* __restrict__ mean,
                                                       const float* __restrict__ var,
                                                       const unsigned short* __restrict__ wt2,
                                                       unsigned short* __restrict__ hwsb2, int n) {
    __shared__ unsigned short H1[16][ASTR];
    __shared__ unsigned short C2[16][ASTR];
    int t = threadIdx.x;
    int wave = t >> 6, lane = t & 63;
    int sl = lane & 15, part = lane >> 4;
    int d = blockIdx.x * 16 + wave * 4 + part;
    bool active = (d < n);
    int e0 = 0, deg = 0;
    if (active) {
        e0 = row_ptr[d];
        deg = degA[d];
    }
    // preload self row + self dis BEFORE the gather: oldest in flight, retire free
    uint4 vs = make_uint4(0, 0, 0, 0);
    float dd = 0.f;
    if (active) {
        vs = *(const uint4*)(zb + ((size_t)d << 7) + (sl << 3));
        dd = dis[d];
    }
    int md = deg;
    md = max(md, __shfl_xor(md, 16));
    md = max(md, __shfl_xor(md, 32));

    f32x2 acc[4];
    #pragma unroll
    for (int i = 0; i < 4; ++i) acc[i] = (f32x2){0.f, 0.f};
    gather_pipe(zb, col16, e0, deg, md, sl, part, acc);

    unsigned outw[4] = {0, 0, 0, 0};
    if (active) {
        const unsigned* w = (const unsigned*)&vs;
        #pragma unroll
        for (int i2 = 0; i2 < 4; ++i2)
            acc[i2] += bf2_to_f32x2(w[i2]);   // zb pre-scaled: self term is zs[d]
        int f0 = sl << 3;
        #pragma unroll
        for (int i2 = 0; i2 < 4; ++i2) {
            int f = f0 + 2 * i2;
            float2 bv = *(const float2*)&bias[f];
            float2 gm = *(const float2*)&gamma[f];
            float2 bt = *(const float2*)&beta[f];
            float2 mn = *(const float2*)&mean[f];
            float2 vr = *(const float2*)&var[f];
            float vx = acc[i2].x * dd + bv.x;
            float vy = acc[i2].y * dd + bv.y;
            float sx = gm.x * rsqrtf(vr.x + BN_EPS);
            float sy = gm.y * rsqrtf(vr.y + BN_EPS);
            float rx = fmaxf((vx - mn.x) * sx + bt.x, 0.f);
            float ry = fmaxf((vy - mn.y) * sy + bt.y, 0.f);
            outw[i2] = pack_bf2(rx, ry);
        }
    }
    int local = wave * 4 + part;
    *(uint4*)&H1[local][sl << 3] = *(uint4*)outw;
    __syncthreads();

    int m = sl;
    int quad = part;
    short8 a2[4];
    #pragma unroll
    for (int kt = 0; kt < 4; ++kt)
        a2[kt] = *(const short8*)&H1[m][kt * 32 + quad * 8];

    f32x4 acc2[2];
    acc2[0] = (f32x4){0.f, 0.f, 0.f, 0.f};
    acc2[1] = (f32x4){0.f, 0.f, 0.f, 0.f};
    #pragma unroll
    for (int i = 0; i < 2; ++i) {
        int ct = wave * 2 + i;
        const unsigned short* wb = &wt2[(size_t)(ct * 16 + m) * 128 + quad * 8];
        #pragma unroll
        for (int kt = 0; kt < 4; ++kt) {
            short8 b = *(const short8*)(wb + kt * 32);
            acc2[i] = __builtin_amdgcn_mfma_f32_16x16x32_bf16(a2[kt], b, acc2[i], 0, 0, 0);
        }
    }
    int gr = blockIdx.x * 16 + quad * 4;
    float ds2[4];
    #pragma unroll
    for (int reg = 0; reg < 4; ++reg)
        ds2[reg] = (gr + reg < n) ? dis[gr + reg] : 0.f;
    #pragma unroll
    for (int i = 0; i < 2; ++i) {
        int col = (wave * 2 + i) * 16 + m;
        #pragma unroll
        for (int reg = 0; reg < 4; ++reg)
            C2[quad * 4 + reg][col] = bf16_1(acc2[i][reg] * ds2[reg]);
    }
    __syncthreads();
    {
        int r = t >> 4;
        int c8 = (t & 15) * 8;
        int grow = blockIdx.x * 16 + r;
        if (grow < n)
            *(uint4*)&hwsb2[(size_t)grow * 128 + c8] = *(const uint4*)&C2[r][c8];
    }
}

// ------- layer-2 agg + BN + ReLU + attention + logits; block=256, 16 nodes -------

__global__ __launch_bounds__(256, 3) void k_agg2_att_logit(const unsigned short* __restrict__ hwsb,
                                                           const int* __restrict__ row_ptr,
                                                           const int* __restrict__ degA,
                                                           const unsigned short* __restrict__ col16,
                                                           const float* __restrict__ dis,
                                                           const float* __restrict__ bias,
                                                           const float* __restrict__ gamma,
                                                           const float* __restrict__ beta,
                                                           const float* __restrict__ mean,
                                                           const float* __restrict__ var,
                                                           const int* __restrict__ batch,
                                                           const float* __restrict__ att_w,
                                                           const float* __restrict__ cls_w,
                                                           float* __restrict__ att_out,
                                                           float* __restrict__ logits, int n) {
    __shared__ int   sg[16];
    __shared__ float sv[16];
    int t = threadIdx.x;
    int wave = t >> 6, lane = t & 63;
    int sl = lane & 15, part = lane >> 4;
    int d = blockIdx.x * 16 + wave * 4 + part;
    bool active = (d < n);
    int e0 = 0, deg = 0;
    if (active) {
        e0 = row_ptr[d];
        deg = degA[d];
    }
    // preload self row, self dis, and batch id BEFORE the gather
    uint4 vs = make_uint4(0, 0, 0, 0);
    float dd = 0.f;
    int g = -1;
    if (active) {
        vs = *(const uint4*)(hwsb + ((size_t)d << 7) + (sl << 3));
        dd = dis[d];
        g = batch[d];
    }
    int md = deg;
    md = max(md, __shfl_xor(md, 16));
    md = max(md, __shfl_xor(md, 32));

    f32x2 acc[4];
    #pragma unroll
    for (int i = 0; i < 4; ++i) acc[i] = (f32x2){0.f, 0.f};
    gather_pipe(hwsb, col16, e0, deg, md, sl, part, acc);

    float contrib = 0.f;
    float p = 0.f, q = 0.f;
    if (active) {
        const unsigned* w = (const unsigned*)&vs;
        #pragma unroll
        for (int i2 = 0; i2 < 4; ++i2)
            acc[i2] += bf2_to_f32x2(w[i2]);
        float dd2 = dd;
        int f0 = sl << 3;
        #pragma unroll
        for (int i2 = 0; i2 < 4; ++i2) {
            int f = f0 + 2 * i2;
            float2 bv = *(const float2*)&bias[f];
            float2 gm = *(const float2*)&gamma[f];
            float2 bt = *(const float2*)&beta[f];
            float2 mn = *(const float2*)&mean[f];
            float2 vr = *(const float2*)&var[f];
            float vx = acc[i2].x * dd2 + bv.x;
            float vy = acc[i2].y * dd2 + bv.y;
            float sx = gm.x * rsqrtf(vr.x + BN_EPS);
            float sy = gm.y * rsqrtf(vr.y + BN_EPS);
            float rx = fmaxf((vx - mn.x) * sx + bt.x, 0.f);
            float ry = fmaxf((vy - mn.y) * sy + bt.y, 0.f);
            float2 aw = *(const float2*)&att_w[f];
            float2 cw = *(const float2*)&cls_w[f];
            p += rx * aw.x + ry * aw.y;
            q += rx * cw.x + ry * cw.y;
        }
    }
    #pragma unroll
    for (int off = 1; off < 16; off <<= 1) {
        p += __shfl_xor(p, off);
        q += __shfl_xor(q, off);
    }
    if (active) {
        float a = 1.f / (1.f + expf(-p));
        if (sl == 0) att_out[d] = a;
        contrib = a * q;
    }
    if (sl == 0) {
        sg[wave * 4 + part] = g;
        sv[wave * 4 + part] = contrib;
    }
    __syncthreads();
    if (t == 0) {
        int cur = -1;
        float acc2 = 0.f;
        #pragma unroll
        for (int i = 0; i < 16; ++i) {
            int gi = sg[i];
            if (gi < 0) continue;
            if (gi != cur) {
                if (cur >= 0) atomicAdd(&logits[cur], acc2);
                cur = gi;
                acc2 = 0.f;
            }
            acc2 += sv[i];
        }
        if (cur >= 0) atomicAdd(&logits[cur], acc2);
    }
}

// ---------------- launch ----------------

extern "C" void kernel_launch(void* const* d_in, const int* in_sizes, int n_in,
                              void* d_out, int out_size, void* d_ws, size_t ws_size,
                              hipStream_t stream) {
    const float* x   = (const float*)d_in[0];
    const int*   ei  = (const int*)d_in[1];
    const int*   bat = (const int*)d_in[2];
    const float* W1  = (const float*)d_in[3];
    const float* b1  = (const float*)d_in[4];
    const float* g1  = (const float*)d_in[5];
    const float* bt1 = (const float*)d_in[6];
    const float* mn1 = (const float*)d_in[7];
    const float* vr1 = (const float*)d_in[8];
    const float* W2  = (const float*)d_in[9];
    const float* b2  = (const float*)d_in[10];
    const float* g2  = (const float*)d_in[11];
    const float* bt2 = (const float*)d_in[12];
    const float* mn2 = (const float*)d_in[13];
    const float* vr2 = (const float*)d_in[14];
    const float* attw = (const float*)d_in[15];
    const float* clsw = (const float*)d_in[16];
    const float* clsb = (const float*)d_in[17];

    int E = in_sizes[1] / 2;
    int n = in_sizes[2];
    const int* src = ei;
    const int* dst = ei + E;
    int NB = (n + 255) >> 8;       // buckets of 256 nodes

    char* ws = (char*)d_ws;
    auto alloc = [&](size_t bytes) {
        void* p = (void*)ws;
        ws += (bytes + 255) & ~(size_t)255;
        return p;
    };
    int*            bcurP   = (int*)alloc(NBKT * 16 * 4);
    unsigned*       bpacked = (unsigned*)alloc((size_t)NBKT * CAP * 4);
    int*            row_ptr = (int*)alloc((size_t)n * 4);
    int*            degA    = (int*)alloc((size_t)n * 4);
    unsigned short* col16   = (unsigned short*)alloc(((size_t)NBKT * CAP + 1024) * 2);
    float*          dis     = (float*)alloc((size_t)n * 4);
    unsigned short* zb      = (unsigned short*)alloc((size_t)n * 128 * 2);
    unsigned short* hwsb2   = (unsigned short*)alloc((size_t)n * 128 * 2);
    unsigned short* wt1     = (unsigned short*)alloc(128 * 128 * 2);
    unsigned short* wt2     = (unsigned short*)alloc(128 * 128 * 2);

    float* out = (float*)d_out;
    int DB = (E + ETILE - 1) / ETILE;
    int gb = (n + 63) / 64;
    int G1A = gb / 2;              // gemm1 rows [0, G1A*64) with distribute
    int G1B = gb - G1A;            // remaining rows with csr sort
    int ab = (n + 15) / 16;
    int sb = (n * 16 + 255) / 256;

    k_prep0<<<257, 128, 0, stream>>>(W1, W2, wt1, wt2, bcurP, clsb, out);
    k_dist_gemm1<<<DB + G1A, 256, 0, stream>>>(src, dst, bcurP, bpacked, x, wt1, zb,
                                               E, n, DB);
    k_csr_gemm1<<<NB + G1B, 256, 0, stream>>>(bpacked, bcurP, row_ptr, degA, dis,
                                              col16, x, wt1, zb, n, NB, G1A * 64);
    k_scale<<<sb, 256, 0, stream>>>(zb, dis, n);
    k_agg1_gemm2<<<ab, 256, 0, stream>>>(zb, row_ptr, degA, col16, dis,
                                         b1, g1, bt1, mn1, vr1, wt2, hwsb2, n);
    k_agg2_att_logit<<<ab, 256, 0, stream>>>(hwsb2, row_ptr, degA, col16, dis,
                                             b2, g2, bt2, mn2, vr2, bat, attw, clsw,
                                             out + NG, out, n);
}

// Round 11
// 255.342 us; speedup vs baseline: 1.0688x; 1.0061x over previous
//
#include <hip/hip_runtime.h>
#include <math.h>

#define NN 50000
#define HID 128
#define NG 64
#define BN_EPS 1e-5f

typedef __attribute__((ext_vector_type(8))) short short8;
typedef __attribute__((ext_vector_type(4))) float f32x4;
typedef __attribute__((ext_vector_type(2))) float f32x2;

// ---- bf16 pack/unpack (RNE) ----
__device__ inline unsigned pack_bf2(float a, float b) {
    union { float f; unsigned u; } ua, ub;
    ua.f = a; ub.f = b;
    unsigned x = ua.u, y = ub.u;
    x += 0x7fffu + ((x >> 16) & 1u);
    y += 0x7fffu + ((y >> 16) & 1u);
    return (x >> 16) | (y & 0xffff0000u);
}
__device__ inline unsigned short bf16_1(float x) {
    union { float f; unsigned u; } v;
    v.f = x;
    unsigned r = v.u + 0x7fffu + ((v.u >> 16) & 1u);
    return (unsigned short)(r >> 16);
}
__device__ inline float2 unpack_bf2(unsigned v) {
    union { unsigned u; float f; } a, b;
    a.u = v << 16;
    b.u = v & 0xffff0000u;
    return make_float2(a.f, b.f);
}
// bf16-pair -> f32x2 (for packed v_pk_add_f32 accumulation)
__device__ __forceinline__ f32x2 bf2_to_f32x2(unsigned u) {
    union { unsigned q; float f; } a, b;
    a.q = u << 16;
    b.q = u & 0xffff0000u;
    f32x2 r;
    r.x = a.f;
    r.y = b.f;
    return r;
}

// =============== CSR build — fixed-capacity buckets ===============
// K = 256 nodes/bucket (pow2). R8's atomic-cursor split-fused form (measured
// best). NEW: per-group-of-4 node segments in col16 are PADDED to a common
// multiple-of-8 length with sentinel index n (a zeroed row appended to
// zb/hwsb2) so the agg gather needs NO bounds predication at all.
#define NBKT 256                 // scan width (buckets used = NB <= 256)
#define ETILE 4096
#define EPT   (ETILE / 256)      // 16 edges per thread
#define CAPB  10240              // bpacked: avg bucket load 8192; +25% headroom
#define CAPC  12800              // col16 (padded): avg ~10900; +17% headroom
#define ASTR 136

// prep: blocks 0..255 W transpose+bf16; block 256 zero cursors + seed logits
//       + zero the sentinel rows (row n) of zb and hwsb2.
__global__ __launch_bounds__(128) void k_prep0(const float* __restrict__ W1,
                                               const float* __restrict__ W2,
                                               unsigned short* __restrict__ wt1,
                                               unsigned short* __restrict__ wt2,
                                               int* __restrict__ bcurP,
                                               const float* __restrict__ cls_b,
                                               float* __restrict__ logits,
                                               unsigned short* __restrict__ zb,
                                               unsigned short* __restrict__ hwsb2,
                                               int n) {
    int b = blockIdx.x;
    int t = threadIdx.x;
    if (b < 256) {
        int k = b & 127;
        const float* W = (b < 128) ? W1 : W2;
        unsigned short* wt = (b < 128) ? wt1 : wt2;
        wt[t * 128 + k] = bf16_1(W[k * 128 + t]);
    } else {
        #pragma unroll
        for (int i = 0; i < 32; ++i) bcurP[t * 32 + i] = 0;
        if (t < NG) logits[t] = cls_b[0];
        if (t < 64) *(unsigned*)((char*)zb + (size_t)n * 256 + t * 4) = 0u;
        else        *(unsigned*)((char*)hwsb2 + (size_t)n * 256 + (t - 64) * 4) = 0u;
    }
}

// ---- shared gemm1 tile body: z[row0..row0+64) = bf16(x@W1), UNSCALED ----
__device__ __forceinline__ void gemm1_tile(char* smem, int row0,
                                           const float* __restrict__ x,
                                           const unsigned short* __restrict__ wt1,
                                           unsigned short* __restrict__ zb,
                                           int n, int t) {
    typedef unsigned short ArowT[ASTR];
    ArowT* A = (ArowT*)smem;
    #pragma unroll
    for (int i = 0; i < 8; ++i) {
        int idx = t + i * 256;
        int r = idx >> 5;
        int c4 = (idx & 31) * 4;
        float4 v = make_float4(0.f, 0.f, 0.f, 0.f);
        if (row0 + r < n) v = *(const float4*)&x[(size_t)(row0 + r) * 128 + c4];
        uint2 p;
        p.x = pack_bf2(v.x, v.y);
        p.y = pack_bf2(v.z, v.w);
        *(uint2*)&A[r][c4] = p;
    }
    __syncthreads();
    int lane = t & 63;
    int wave = t >> 6;
    int m = lane & 15;
    int quad = lane >> 4;
    int r0 = wave * 16;
    short8 a[4];
    #pragma unroll
    for (int kt = 0; kt < 4; ++kt)
        a[kt] = *(const short8*)&A[r0 + m][kt * 32 + quad * 8];
    f32x4 acc[8];
    #pragma unroll
    for (int ct = 0; ct < 8; ++ct) acc[ct] = (f32x4){0.f, 0.f, 0.f, 0.f};
    short8 bcur[4], bnxt[4];
    {
        const unsigned short* wb = &wt1[(size_t)m * 128 + quad * 8];
        #pragma unroll
        for (int kt = 0; kt < 4; ++kt) bcur[kt] = *(const short8*)(wb + kt * 32);
    }
    #pragma unroll
    for (int ct = 0; ct < 8; ++ct) {
        if (ct < 7) {
            const unsigned short* wb = &wt1[(size_t)((ct + 1) * 16 + m) * 128 + quad * 8];
            #pragma unroll
            for (int kt = 0; kt < 4; ++kt) bnxt[kt] = *(const short8*)(wb + kt * 32);
        }
        #pragma unroll
        for (int kt = 0; kt < 4; ++kt)
            acc[ct] = __builtin_amdgcn_mfma_f32_16x16x32_bf16(a[kt], bcur[kt], acc[ct], 0, 0, 0);
        #pragma unroll
        for (int kt = 0; kt < 4; ++kt) bcur[kt] = bnxt[kt];
    }
    __syncthreads();
    #pragma unroll
    for (int ct = 0; ct < 8; ++ct) {
        int col = ct * 16 + m;
        #pragma unroll
        for (int reg = 0; reg < 4; ++reg)
            A[r0 + quad * 4 + reg][col] = bf16_1(acc[ct][reg]);
    }
    __syncthreads();
    #pragma unroll
    for (int i = 0; i < 4; ++i) {
        int idx = t + i * 256;
        int r = idx >> 4;
        int c8 = (idx & 15) * 8;
        int grow = row0 + r;
        if (grow < n)
            *(uint4*)&zb[(size_t)grow * 128 + c8] = *(const uint4*)&A[r][c8];
    }
}

// L2a: blocks [0,DB) = edge distribute (coalesced LDS counting sort);
//      blocks [DB,..) = gemm1 rows [0, G1A*64).
struct SmemDist {
    int h[NBKT], sx[NBKT], cur[NBKT], gb[NBKT];
    unsigned stage[ETILE];
};

__global__ __launch_bounds__(256) void k_dist_gemm1(const int* __restrict__ src,
                                                    const int* __restrict__ dst,
                                                    int* __restrict__ bcurP,
                                                    unsigned* __restrict__ bpacked,
                                                    const float* __restrict__ x,
                                                    const unsigned short* __restrict__ wt1,
                                                    unsigned short* __restrict__ zb,
                                                    int E, int n, int DB) {
    __shared__ __align__(16) char smem[sizeof(SmemDist)];
    int t = threadIdx.x;
    int b = blockIdx.x;

    if (b >= DB) {
        gemm1_tile(smem, (b - DB) * 64, x, wt1, zb, n, t);
        return;
    }
    // ---------------- distribute path ----------------
    SmemDist* s = (SmemDist*)smem;
    s->h[t] = 0;
    __syncthreads();
    int base = b * ETILE;
    int dreg[EPT];
    #pragma unroll
    for (int i = 0; i < EPT; ++i) {
        int e = base + i * 256 + t;
        dreg[i] = (e < E) ? dst[e] : -1;
        if (dreg[i] >= 0) atomicAdd(&s->h[dreg[i] >> 8], 1);
    }
    __syncthreads();
    int c = s->h[t];
    s->sx[t] = c;
    __syncthreads();
    for (int off = 1; off < NBKT; off <<= 1) {
        int v = (t >= off) ? s->sx[t - off] : 0;
        __syncthreads();
        s->sx[t] += v;
        __syncthreads();
    }
    int nvalid = s->sx[NBKT - 1];
    int excl = s->sx[t] - c;
    __syncthreads();
    s->sx[t] = excl;
    s->cur[t] = excl;
    s->gb[t] = (c > 0) ? atomicAdd(&bcurP[t * 16], c) : 0;
    __syncthreads();
    #pragma unroll
    for (int i = 0; i < EPT; ++i) {
        int e = base + i * 256 + t;
        if (dreg[i] >= 0) {
            int d = dreg[i];
            int bkt = d >> 8;
            int p = atomicAdd(&s->cur[bkt], 1);
            s->stage[p] = ((unsigned)d << 16) | (unsigned)src[e];
        }
    }
    __syncthreads();
    for (int idx = t; idx < nvalid; idx += 256) {
        unsigned v = s->stage[idx];
        int bkt = (int)(v >> 24);
        int pos = s->gb[bkt] + (idx - s->sx[bkt]);
        bpacked[(size_t)bkt * CAPB + pos] = v;
    }
}

// L2b: blocks [0,NB) = bucket CSR counting sort with GROUP-OF-4 PADDING
//      (ushort col16, sentinel-filled gaps, LDS-staged coalesced writes);
//      blocks [NB,..) = gemm1 rows [G1A*64, n).
// degA stores the PADDED length (multiple of 8, uniform over each aligned
// group of 4 nodes); dis stores rsqrt(real_deg+1).
struct SmemCSR {
    int cnt[NBKT], sA[NBKT], cur[NBKT];
    unsigned short stage[CAPC];
};

__global__ __launch_bounds__(256) void k_csr_gemm1(const unsigned* __restrict__ bpacked,
                                                   const int* __restrict__ bcurP,
                                                   int* __restrict__ row_ptr,
                                                   int* __restrict__ degA,
                                                   float* __restrict__ dis,
                                                   unsigned short* __restrict__ col16,
                                                   const float* __restrict__ x,
                                                   const unsigned short* __restrict__ wt1,
                                                   unsigned short* __restrict__ zb,
                                                   int n, int NB, int row0B) {
    __shared__ __align__(16) char smem[sizeof(SmemCSR)];
    int t = threadIdx.x;
    int b = blockIdx.x;

    if (b >= NB) {
        gemm1_tile(smem, row0B + (b - NB) * 64, x, wt1, zb, n, t);
        return;
    }
    // ---------------- bucket CSR path ----------------
    SmemCSR* s = (SmemCSR*)smem;
    int node0 = b << 8;
    int nn = n - node0;
    if (nn > 256) nn = 256;
    if (nn < 0) nn = 0;
    int e0 = b * CAPB;            // bpacked segment
    int e0c = b * CAPC;           // col16 (padded) segment
    int ne = bcurP[b * 16];
    s->cnt[t] = 0;
    __syncthreads();
    int n4 = (ne + 3) >> 2;
    for (int i = t; i < n4; i += 256) {
        uint4 v = *(const uint4*)&bpacked[e0 + 4 * i];
        int rem = ne - 4 * i;
        if (rem > 0) atomicAdd(&s->cnt[(v.x >> 16) & 255u], 1);
        if (rem > 1) atomicAdd(&s->cnt[(v.y >> 16) & 255u], 1);
        if (rem > 2) atomicAdd(&s->cnt[(v.z >> 16) & 255u], 1);
        if (rem > 3) atomicAdd(&s->cnt[(v.w >> 16) & 255u], 1);
    }
    __syncthreads();
    int c = s->cnt[t];
    // group-of-4 max, rounded up to multiple of 8 -> padded length P
    int gm = max(c, __shfl_xor(c, 1));
    gm = max(gm, __shfl_xor(gm, 2));
    int P = (gm + 7) & ~7;
    s->sA[t] = P;
    __syncthreads();
    for (int off = 1; off < NBKT; off <<= 1) {
        int v = (t >= off) ? s->sA[t - off] : 0;
        __syncthreads();
        s->sA[t] += v;
        __syncthreads();
    }
    int excl = s->sA[t] - P;
    s->cur[t] = excl;
    if (t < nn) {
        row_ptr[node0 + t] = e0c + excl;
        degA[node0 + t] = P;                      // padded length
        dis[node0 + t] = rsqrtf((float)(c + 1));  // real degree
    }
    __syncthreads();
    int totP = s->sA[NBKT - 1];
    // sentinel-init the whole padded region (index n -> zero row)
    unsigned short sent = (unsigned short)n;
    for (int i = t; i < totP; i += 256) s->stage[i] = sent;
    __syncthreads();
    for (int i = t; i < n4; i += 256) {
        uint4 v = *(const uint4*)&bpacked[e0 + 4 * i];
        int rem = ne - 4 * i;
        unsigned vv[4] = {v.x, v.y, v.z, v.w};
        #pragma unroll
        for (int j = 0; j < 4; ++j) {
            if (rem > j) {
                int ld = (int)((vv[j] >> 16) & 255u);
                int p = atomicAdd(&s->cur[ld], 1);
                s->stage[p] = (unsigned short)(vv[j] & 0xFFFFu);
            }
        }
    }
    __syncthreads();
    // coalesced flush of the whole padded segment (2 ushort per uint store)
    int nw = totP >> 1;   // totP is a multiple of 8
    for (int i = t; i < nw; i += 256) {
        unsigned w = (unsigned)s->stage[2 * i] | ((unsigned)s->stage[2 * i + 1] << 16);
        *(unsigned*)&col16[e0c + 2 * i] = w;
    }
}

// pre-scale zb rows by dis[row] (= rsqrt(deg+1)).
__global__ __launch_bounds__(256) void k_scale(unsigned short* __restrict__ zb,
                                               const float* __restrict__ dis, int n) {
    int i = blockIdx.x * 256 + threadIdx.x;
    int r = i >> 4;
    if (r >= n) return;
    int c8 = (i & 15) * 8;
    float s = dis[r];
    uint4 v = *(const uint4*)&zb[(size_t)r * 128 + c8];
    unsigned* w = (unsigned*)&v;
    #pragma unroll
    for (int k = 0; k < 4; ++k) {
        float2 f = unpack_bf2(w[k]);
        w[k] = pack_bf2(f.x * s, f.y * s);
    }
    *(uint4*)&zb[(size_t)r * 128 + c8] = v;
}

// =============== gather core: 16 lanes/node, 8-edge tiles, shuffle indices ===============
// Fully UNCONDITIONAL gather: segments are sentinel-padded (index n -> zeroed
// row), so there is no bounds predication on idx loads, row loads, or consume.
// R4-proven 2-buffer pipeline + pk_add_f32 consume. VGPR stays < 64 (8 w/SIMD).

__device__ __forceinline__ void consume8(const uint4* v, f32x2* acc) {
    #pragma unroll
    for (int j = 0; j < 8; ++j) {
        const unsigned* w = (const unsigned*)&v[j];
        #pragma unroll
        for (int i2 = 0; i2 < 4; ++i2)
            acc[i2] += bf2_to_f32x2(w[i2]);
    }
}

__device__ __forceinline__ void issue8(const unsigned short* __restrict__ hws,
                                       int sl, int lsel, int creg, uint4* v) {
    #pragma unroll
    for (int j = 0; j < 8; ++j) {
        int s = __shfl(creg, lsel + j);
        v[j] = *(const uint4*)(hws + ((size_t)s << 7) + (sl << 3));
    }
}

__device__ __forceinline__ void gather_pipe(const unsigned short* __restrict__ hws,
                                            const unsigned short* __restrict__ col16,
                                            int e0, int P, int sl, int part,
                                            f32x2* acc) {
    int nt = P >> 3;
    if (nt <= 0) return;
    int base = part << 4;
    uint4 vA[8], vB[8];
    int c0 = (int)col16[e0 + sl];
    int c1 = (int)col16[e0 + 16 + sl];
    int n0 = 0, n1 = 0;

    issue8(hws, sl, base, c0, vA);      // tile 0
    int t = 0, ebase = 0;
    for (;;) {
        // ---- phase0: tile t (==0 mod 4) in vA ----
        if (t + 4 < nt) {   // prefetch next macro's indices FIRST (oldest for counted wait)
            n0 = (int)col16[e0 + ebase + 32 + sl];
            n1 = (int)col16[e0 + ebase + 48 + sl];
        }
        if (t + 1 < nt) issue8(hws, sl, base + 8, c0, vB);
        consume8(vA, acc);
        if (++t >= nt) break;
        // ---- phase1: tile t in vB ----
        if (t + 1 < nt) issue8(hws, sl, base, c1, vA);
        consume8(vB, acc);
        if (++t >= nt) break;
        // ---- phase2: tile t in vA ----
        if (t + 1 < nt) issue8(hws, sl, base + 8, c1, vB);
        consume8(vA, acc);
        if (++t >= nt) break;
        // ---- phase3: tile t in vB; next tile uses the prefetched n0 ----
        if (t + 1 < nt) issue8(hws, sl, base, n0, vA);
        consume8(vB, acc);
        if (++t >= nt) break;
        c0 = n0; c1 = n1; ebase += 32;
    }
}

// ------- FUSED: layer-1 agg (unscaled gather of pre-scaled zb) + BN + ReLU
//         -> h1 (LDS) -> GEMM2 -> hws2 (pre-scaled) -------

__global__ __launch_bounds__(256, 3) void k_agg1_gemm2(const unsigned short* __restrict__ zb,
                                                       const int* __restrict__ row_ptr,
                                                       const int* __restrict__ degA,
                                                       const unsigned short* __restrict__ col16,
                                                       const float* __restrict__ dis,
                                                       const float* __restrict__ bias,
                                                       const float* __restrict__ gamma,
                                                       const float* __restrict__ beta,
                                                       const float* __restrict__ mean,
                                                       const float* __restrict__ var,
                                                       const unsigned short* __restrict__ wt2,
                                                       unsigned short* __restrict__ hwsb2, int n) {
    __shared__ unsigned short H1[16][ASTR];
    __shared__ unsigned short C2[16][ASTR];
    int t = threadIdx.x;
    int wave = t >> 6, lane = t & 63;
    int sl = lane & 15, part = lane >> 4;
    int d = blockIdx.x * 16 + wave * 4 + part;
    bool active = (d < n);
    int e0 = 0, P = 0;
    if (active) {
        e0 = row_ptr[d];
        P = degA[d];     // padded length, uniform across the group of 4
    }
    // preload self row + self dis BEFORE the gather: oldest in flight, retire free
    uint4 vs = make_uint4(0, 0, 0, 0);
    float dd = 0.f;
    if (active) {
        vs = *(const uint4*)(zb + ((size_t)d << 7) + (sl << 3));
        dd = dis[d];
    }
    int md = P;
    md = max(md, __shfl_xor(md, 16));
    md = max(md, __shfl_xor(md, 32));

    f32x2 acc[4];
    #pragma unroll
    for (int i = 0; i < 4; ++i) acc[i] = (f32x2){0.f, 0.f};
    gather_pipe(zb, col16, e0, md, sl, part, acc);

    unsigned outw[4] = {0, 0, 0, 0};
    if (active) {
        const unsigned* w = (const unsigned*)&vs;
        #pragma unroll
        for (int i2 = 0; i2 < 4; ++i2)
            acc[i2] += bf2_to_f32x2(w[i2]);   // zb pre-scaled: self term is zs[d]
        int f0 = sl << 3;
        #pragma unroll
        for (int i2 = 0; i2 < 4; ++i2) {
            int f = f0 + 2 * i2;
            float2 bv = *(const float2*)&bias[f];
            float2 gm = *(const float2*)&gamma[f];
            float2 bt = *(const float2*)&beta[f];
            float2 mn = *(const float2*)&mean[f];
            float2 vr = *(const float2*)&var[f];
            float vx = acc[i2].x * dd + bv.x;
            float vy = acc[i2].y * dd + bv.y;
            float sx = gm.x * rsqrtf(vr.x + BN_EPS);
            float sy = gm.y * rsqrtf(vr.y + BN_EPS);
            float rx = fmaxf((vx - mn.x) * sx + bt.x, 0.f);
            float ry = fmaxf((vy - mn.y) * sy + bt.y, 0.f);
            outw[i2] = pack_bf2(rx, ry);
        }
    }
    int local = wave * 4 + part;
    *(uint4*)&H1[local][sl << 3] = *(uint4*)outw;
    __syncthreads();

    int m = sl;
    int quad = part;
    short8 a2[4];
    #pragma unroll
    for (int kt = 0; kt < 4; ++kt)
        a2[kt] = *(const short8*)&H1[m][kt * 32 + quad * 8];

    f32x4 acc2[2];
    acc2[0] = (f32x4){0.f, 0.f, 0.f, 0.f};
    acc2[1] = (f32x4){0.f, 0.f, 0.f, 0.f};
    #pragma unroll
    for (int i = 0; i < 2; ++i) {
        int ct = wave * 2 + i;
        const unsigned short* wb = &wt2[(size_t)(ct * 16 + m) * 128 + quad * 8];
        #pragma unroll
        for (int kt = 0; kt < 4; ++kt) {
            short8 b = *(const short8*)(wb + kt * 32);
            acc2[i] = __builtin_amdgcn_mfma_f32_16x16x32_bf16(a2[kt], b, acc2[i], 0, 0, 0);
        }
    }
    int gr = blockIdx.x * 16 + quad * 4;
    float ds2[4];
    #pragma unroll
    for (int reg = 0; reg < 4; ++reg)
        ds2[reg] = (gr + reg < n) ? dis[gr + reg] : 0.f;
    #pragma unroll
    for (int i = 0; i < 2; ++i) {
        int col = (wave * 2 + i) * 16 + m;
        #pragma unroll
        for (int reg = 0; reg < 4; ++reg)
            C2[quad * 4 + reg][col] = bf16_1(acc2[i][reg] * ds2[reg]);
    }
    __syncthreads();
    {
        int r = t >> 4;
        int c8 = (t & 15) * 8;
        int grow = blockIdx.x * 16 + r;
        if (grow < n)
            *(uint4*)&hwsb2[(size_t)grow * 128 + c8] = *(const uint4*)&C2[r][c8];
    }
}

// ------- layer-2 agg + BN + ReLU + attention + logits; block=256, 16 nodes -------

__global__ __launch_bounds__(256, 3) void k_agg2_att_logit(const unsigned short* __restrict__ hwsb,
                                                           const int* __restrict__ row_ptr,
                                                           const int* __restrict__ degA,
                                                           const unsigned short* __restrict__ col16,
                                                           const float* __restrict__ dis,
                                                           const float* __restrict__ bias,
                                                           const float* __restrict__ gamma,
                                                           const float* __restrict__ beta,
                                                           const float* __restrict__ mean,
                                                           const float* __restrict__ var,
                                                           const int* __restrict__ batch,
                                                           const float* __restrict__ att_w,
                                                           const float* __restrict__ cls_w,
                                                           float* __restrict__ att_out,
                                                           float* __restrict__ logits, int n) {
    __shared__ int   sg[16];
    __shared__ float sv[16];
    int t = threadIdx.x;
    int wave = t >> 6, lane = t & 63;
    int sl = lane & 15, part = lane >> 4;
    int d = blockIdx.x * 16 + wave * 4 + part;
    bool active = (d < n);
    int e0 = 0, P = 0;
    if (active) {
        e0 = row_ptr[d];
        P = degA[d];
    }
    // preload self row, self dis, and batch id BEFORE the gather
    uint4 vs = make_uint4(0, 0, 0, 0);
    float dd = 0.f;
    int g = -1;
    if (active) {
        vs = *(const uint4*)(hwsb + ((size_t)d << 7) + (sl << 3));
        dd = dis[d];
        g = batch[d];
    }
    int md = P;
    md = max(md, __shfl_xor(md, 16));
    md = max(md, __shfl_xor(md, 32));

    f32x2 acc[4];
    #pragma unroll
    for (int i = 0; i < 4; ++i) acc[i] = (f32x2){0.f, 0.f};
    gather_pipe(hwsb, col16, e0, md, sl, part, acc);

    float contrib = 0.f;
    float p = 0.f, q = 0.f;
    if (active) {
        const unsigned* w = (const unsigned*)&vs;
        #pragma unroll
        for (int i2 = 0; i2 < 4; ++i2)
            acc[i2] += bf2_to_f32x2(w[i2]);
        float dd2 = dd;
        int f0 = sl << 3;
        #pragma unroll
        for (int i2 = 0; i2 < 4; ++i2) {
            int f = f0 + 2 * i2;
            float2 bv = *(const float2*)&bias[f];
            float2 gm = *(const float2*)&gamma[f];
            float2 bt = *(const float2*)&beta[f];
            float2 mn = *(const float2*)&mean[f];
            float2 vr = *(const float2*)&var[f];
            float vx = acc[i2].x * dd2 + bv.x;
            float vy = acc[i2].y * dd2 + bv.y;
            float sx = gm.x * rsqrtf(vr.x + BN_EPS);
            float sy = gm.y * rsqrtf(vr.y + BN_EPS);
            float rx = fmaxf((vx - mn.x) * sx + bt.x, 0.f);
            float ry = fmaxf((vy - mn.y) * sy + bt.y, 0.f);
            float2 aw = *(const float2*)&att_w[f];
            float2 cw = *(const float2*)&cls_w[f];
            p += rx * aw.x + ry * aw.y;
            q += rx * cw.x + ry * cw.y;
        }
    }
    #pragma unroll
    for (int off = 1; off < 16; off <<= 1) {
        p += __shfl_xor(p, off);
        q += __shfl_xor(q, off);
    }
    if (active) {
        float a = 1.f / (1.f + expf(-p));
        if (sl == 0) att_out[d] = a;
        contrib = a * q;
    }
    if (sl == 0) {
        sg[wave * 4 + part] = g;
        sv[wave * 4 + part] = contrib;
    }
    __syncthreads();
    if (t == 0) {
        int cur = -1;
        float acc2 = 0.f;
        #pragma unroll
        for (int i = 0; i < 16; ++i) {
            int gi = sg[i];
            if (gi < 0) continue;
            if (gi != cur) {
                if (cur >= 0) atomicAdd(&logits[cur], acc2);
                cur = gi;
                acc2 = 0.f;
            }
            acc2 += sv[i];
        }
        if (cur >= 0) atomicAdd(&logits[cur], acc2);
    }
}

// ---------------- launch ----------------

extern "C" void kernel_launch(void* const* d_in, const int* in_sizes, int n_in,
                              void* d_out, int out_size, void* d_ws, size_t ws_size,
                              hipStream_t stream) {
    const float* x   = (const float*)d_in[0];
    const int*   ei  = (const int*)d_in[1];
    const int*   bat = (const int*)d_in[2];
    const float* W1  = (const float*)d_in[3];
    const float* b1  = (const float*)d_in[4];
    const float* g1  = (const float*)d_in[5];
    const float* bt1 = (const float*)d_in[6];
    const float* mn1 = (const float*)d_in[7];
    const float* vr1 = (const float*)d_in[8];
    const float* W2  = (const float*)d_in[9];
    const float* b2  = (const float*)d_in[10];
    const float* g2  = (const float*)d_in[11];
    const float* bt2 = (const float*)d_in[12];
    const float* mn2 = (const float*)d_in[13];
    const float* vr2 = (const float*)d_in[14];
    const float* attw = (const float*)d_in[15];
    const float* clsw = (const float*)d_in[16];
    const float* clsb = (const float*)d_in[17];

    int E = in_sizes[1] / 2;
    int n = in_sizes[2];
    const int* src = ei;
    const int* dst = ei + E;
    int NB = (n + 255) >> 8;       // buckets of 256 nodes

    char* ws = (char*)d_ws;
    auto alloc = [&](size_t bytes) {
        void* p = (void*)ws;
        ws += (bytes + 255) & ~(size_t)255;
        return p;
    };
    int*            bcurP   = (int*)alloc(NBKT * 16 * 4);
    unsigned*       bpacked = (unsigned*)alloc((size_t)NBKT * CAPB * 4);
    int*            row_ptr = (int*)alloc((size_t)n * 4);
    int*            degA    = (int*)alloc((size_t)n * 4);
    unsigned short* col16   = (unsigned short*)alloc(((size_t)NBKT * CAPC + 1024) * 2);
    float*          dis     = (float*)alloc((size_t)n * 4);
    unsigned short* zb      = (unsigned short*)alloc((size_t)(n + 1) * 128 * 2);
    unsigned short* hwsb2   = (unsigned short*)alloc((size_t)(n + 1) * 128 * 2);
    unsigned short* wt1     = (unsigned short*)alloc(128 * 128 * 2);
    unsigned short* wt2     = (unsigned short*)alloc(128 * 128 * 2);

    float* out = (float*)d_out;
    int DB = (E + ETILE - 1) / ETILE;
    int gb = (n + 63) / 64;
    int G1A = gb / 2;              // gemm1 rows [0, G1A*64) with distribute
    int G1B = gb - G1A;            // remaining rows with csr sort
    int ab = (n + 15) / 16;
    int sb = (n * 16 + 255) / 256;

    k_prep0<<<257, 128, 0, stream>>>(W1, W2, wt1, wt2, bcurP, clsb, out, zb, hwsb2, n);
    k_dist_gemm1<<<DB + G1A, 256, 0, stream>>>(src, dst, bcurP, bpacked, x, wt1, zb,
                                               E, n, DB);
    k_csr_gemm1<<<NB + G1B, 256, 0, stream>>>(bpacked, bcurP, row_ptr, degA, dis,
                                              col16, x, wt1, zb, n, NB, G1A * 64);
    k_scale<<<sb, 256, 0, stream>>>(zb, dis, n);
    k_agg1_gemm2<<<ab, 256, 0, stream>>>(zb, row_ptr, degA, col16, dis,
                                         b1, g1, bt1, mn1, vr1, wt2, hwsb2, n);
    k_agg2_att_logit<<<ab, 256, 0, stream>>>(hwsb2, row_ptr, degA, col16, dis,
                                             b2, g2, bt2, mn2, vr2, bat, attw, clsw,
                                             out + NG, out, n);
}

// Round 12
// 254.364 us; speedup vs baseline: 1.0729x; 1.0038x over previous
//
#include <hip/hip_runtime.h>
#include <math.h>

#define NN 50000
#define HID 128
#define NG 64
#define BN_EPS 1e-5f

typedef __attribute__((ext_vector_type(8))) short short8;
typedef __attribute__((ext_vector_type(4))) float f32x4;
typedef __attribute__((ext_vector_type(2))) float f32x2;

// ---- bf16 pack/unpack (RNE) ----
__device__ inline unsigned pack_bf2(float a, float b) {
    union { float f; unsigned u; } ua, ub;
    ua.f = a; ub.f = b;
    unsigned x = ua.u, y = ub.u;
    x += 0x7fffu + ((x >> 16) & 1u);
    y += 0x7fffu + ((y >> 16) & 1u);
    return (x >> 16) | (y & 0xffff0000u);
}
__device__ inline unsigned short bf16_1(float x) {
    union { float f; unsigned u; } v;
    v.f = x;
    unsigned r = v.u + 0x7fffu + ((v.u >> 16) & 1u);
    return (unsigned short)(r >> 16);
}
__device__ inline float2 unpack_bf2(unsigned v) {
    union { unsigned u; float f; } a, b;
    a.u = v << 16;
    b.u = v & 0xffff0000u;
    return make_float2(a.f, b.f);
}
// bf16-pair -> f32x2 (for packed v_pk_add_f32 accumulation)
__device__ __forceinline__ f32x2 bf2_to_f32x2(unsigned u) {
    union { unsigned q; float f; } a, b;
    a.q = u << 16;
    b.q = u & 0xffff0000u;
    f32x2 r;
    r.x = a.f;
    r.y = b.f;
    return r;
}

// =============== CSR build — fixed-capacity buckets ===============
// K = 256 nodes/bucket (pow2). R8's atomic-cursor split-fused form (measured
// best). Group-of-4 node segments in col16 PADDED to a common multiple-of-8
// length with sentinel index n (zeroed row appended to zb/hwsb2) so the agg
// gather is fully unconditional (R11, −3 us on agg2).
#define NBKT 256                 // scan width (buckets used = NB <= 256)
#define ETILE 4096
#define EPT   (ETILE / 256)      // 16 edges per thread
#define CAPB  10240              // bpacked: avg bucket load 8192; +25% headroom
#define CAPC  12800              // col16 (padded): avg ~10900; +17% headroom
#define ASTR 136

// prep: blocks 0,1 = LDS-staged coalesced W transpose; block 2 = cursors +
// logits seed + sentinel rows of zb/hwsb2.
__global__ __launch_bounds__(256) void k_prep0(const float* __restrict__ W1,
                                               const float* __restrict__ W2,
                                               unsigned short* __restrict__ wt1,
                                               unsigned short* __restrict__ wt2,
                                               int* __restrict__ bcurP,
                                               const float* __restrict__ cls_b,
                                               float* __restrict__ logits,
                                               unsigned short* __restrict__ zb,
                                               unsigned short* __restrict__ hwsb2,
                                               int n) {
    int b = blockIdx.x;
    int t = threadIdx.x;
    if (b < 2) {
        __shared__ unsigned short T[128][130];
        const float* W = b ? W2 : W1;
        unsigned short* wt = b ? wt2 : wt1;
        #pragma unroll
        for (int i = 0; i < 64; ++i) {
            int idx = i * 256 + t;
            int r = idx >> 7, c = idx & 127;
            T[c][r] = bf16_1(W[r * 128 + c]);   // coalesced read; LDS scatter
        }
        __syncthreads();
        #pragma unroll
        for (int i = 0; i < 32; ++i) {
            int idx = i * 256 + t;              // uint index, 8192 total
            int r = idx >> 6, c2 = (idx & 63) * 2;
            unsigned w = (unsigned)T[r][c2] | ((unsigned)T[r][c2 + 1] << 16);
            *(unsigned*)&wt[r * 128 + c2] = w;  // coalesced 4B writes
        }
    } else {
        #pragma unroll
        for (int i = 0; i < 16; ++i) bcurP[t * 16 + i] = 0;
        if (t < NG) logits[t] = cls_b[0];
        if (t < 64) *(unsigned*)((char*)zb + (size_t)n * 256 + t * 4) = 0u;
        else if (t < 128) *(unsigned*)((char*)hwsb2 + (size_t)n * 256 + (t - 64) * 4) = 0u;
    }
}

// ---- shared gemm1 tile body: z[row0..row0+64) = bf16(x@W1), UNSCALED ----
__device__ __forceinline__ void gemm1_tile(char* smem, int row0,
                                           const float* __restrict__ x,
                                           const unsigned short* __restrict__ wt1,
                                           unsigned short* __restrict__ zb,
                                           int n, int t) {
    typedef unsigned short ArowT[ASTR];
    ArowT* A = (ArowT*)smem;
    #pragma unroll
    for (int i = 0; i < 8; ++i) {
        int idx = t + i * 256;
        int r = idx >> 5;
        int c4 = (idx & 31) * 4;
        float4 v = make_float4(0.f, 0.f, 0.f, 0.f);
        if (row0 + r < n) v = *(const float4*)&x[(size_t)(row0 + r) * 128 + c4];
        uint2 p;
        p.x = pack_bf2(v.x, v.y);
        p.y = pack_bf2(v.z, v.w);
        *(uint2*)&A[r][c4] = p;
    }
    __syncthreads();
    int lane = t & 63;
    int wave = t >> 6;
    int m = lane & 15;
    int quad = lane >> 4;
    int r0 = wave * 16;
    short8 a[4];
    #pragma unroll
    for (int kt = 0; kt < 4; ++kt)
        a[kt] = *(const short8*)&A[r0 + m][kt * 32 + quad * 8];
    f32x4 acc[8];
    #pragma unroll
    for (int ct = 0; ct < 8; ++ct) acc[ct] = (f32x4){0.f, 0.f, 0.f, 0.f};
    short8 bcur[4], bnxt[4];
    {
        const unsigned short* wb = &wt1[(size_t)m * 128 + quad * 8];
        #pragma unroll
        for (int kt = 0; kt < 4; ++kt) bcur[kt] = *(const short8*)(wb + kt * 32);
    }
    #pragma unroll
    for (int ct = 0; ct < 8; ++ct) {
        if (ct < 7) {
            const unsigned short* wb = &wt1[(size_t)((ct + 1) * 16 + m) * 128 + quad * 8];
            #pragma unroll
            for (int kt = 0; kt < 4; ++kt) bnxt[kt] = *(const short8*)(wb + kt * 32);
        }
        #pragma unroll
        for (int kt = 0; kt < 4; ++kt)
            acc[ct] = __builtin_amdgcn_mfma_f32_16x16x32_bf16(a[kt], bcur[kt], acc[ct], 0, 0, 0);
        #pragma unroll
        for (int kt = 0; kt < 4; ++kt) bcur[kt] = bnxt[kt];
    }
    __syncthreads();
    #pragma unroll
    for (int ct = 0; ct < 8; ++ct) {
        int col = ct * 16 + m;
        #pragma unroll
        for (int reg = 0; reg < 4; ++reg)
            A[r0 + quad * 4 + reg][col] = bf16_1(acc[ct][reg]);
    }
    __syncthreads();
    #pragma unroll
    for (int i = 0; i < 4; ++i) {
        int idx = t + i * 256;
        int r = idx >> 4;
        int c8 = (idx & 15) * 8;
        int grow = row0 + r;
        if (grow < n)
            *(uint4*)&zb[(size_t)grow * 128 + c8] = *(const uint4*)&A[r][c8];
    }
}

// L2a: blocks [0,DB) = edge distribute (coalesced LDS counting sort);
//      blocks [DB,..) = ALL gemm1 tiles (zb fully written by end of launch).
struct SmemDist {
    int h[NBKT], sx[NBKT], cur[NBKT], gb[NBKT];
    unsigned stage[ETILE];
};

__global__ __launch_bounds__(256) void k_dist_gemm1(const int* __restrict__ src,
                                                    const int* __restrict__ dst,
                                                    int* __restrict__ bcurP,
                                                    unsigned* __restrict__ bpacked,
                                                    const float* __restrict__ x,
                                                    const unsigned short* __restrict__ wt1,
                                                    unsigned short* __restrict__ zb,
                                                    int E, int n, int DB) {
    __shared__ __align__(16) char smem[sizeof(SmemDist)];
    int t = threadIdx.x;
    int b = blockIdx.x;

    if (b >= DB) {
        gemm1_tile(smem, (b - DB) * 64, x, wt1, zb, n, t);
        return;
    }
    // ---------------- distribute path ----------------
    SmemDist* s = (SmemDist*)smem;
    s->h[t] = 0;
    __syncthreads();
    int base = b * ETILE;
    int dreg[EPT];
    #pragma unroll
    for (int i = 0; i < EPT; ++i) {
        int e = base + i * 256 + t;
        dreg[i] = (e < E) ? dst[e] : -1;
        if (dreg[i] >= 0) atomicAdd(&s->h[dreg[i] >> 8], 1);
    }
    __syncthreads();
    int c = s->h[t];
    s->sx[t] = c;
    __syncthreads();
    for (int off = 1; off < NBKT; off <<= 1) {
        int v = (t >= off) ? s->sx[t - off] : 0;
        __syncthreads();
        s->sx[t] += v;
        __syncthreads();
    }
    int nvalid = s->sx[NBKT - 1];
    int excl = s->sx[t] - c;
    __syncthreads();
    s->sx[t] = excl;
    s->cur[t] = excl;
    s->gb[t] = (c > 0) ? atomicAdd(&bcurP[t * 16], c) : 0;
    __syncthreads();
    #pragma unroll
    for (int i = 0; i < EPT; ++i) {
        int e = base + i * 256 + t;
        if (dreg[i] >= 0) {
            int d = dreg[i];
            int bkt = d >> 8;
            int p = atomicAdd(&s->cur[bkt], 1);
            s->stage[p] = ((unsigned)d << 16) | (unsigned)src[e];
        }
    }
    __syncthreads();
    for (int idx = t; idx < nvalid; idx += 256) {
        unsigned v = s->stage[idx];
        int bkt = (int)(v >> 24);
        int pos = s->gb[bkt] + (idx - s->sx[bkt]);
        bpacked[(size_t)bkt * CAPB + pos] = v;
    }
}

// L2b: bucket CSR counting sort with GROUP-OF-4 PADDING (ushort col16,
// sentinel-filled gaps, LDS-staged coalesced writes) + FUSED zb pre-scale by
// rsqrt(deg+1) for this bucket's own nodes (race-free: all gemm1 tiles ran in
// L2a; each block owns a disjoint 256-node range).
// degA stores the PADDED length; dis stores rsqrt(real_deg+1).
struct SmemCSR {
    int cnt[NBKT], sA[NBKT], cur[NBKT];
    float disL[NBKT];
    unsigned short stage[CAPC];
};

__global__ __launch_bounds__(256) void k_csr_scale(const unsigned* __restrict__ bpacked,
                                                   const int* __restrict__ bcurP,
                                                   int* __restrict__ row_ptr,
                                                   int* __restrict__ degA,
                                                   float* __restrict__ dis,
                                                   unsigned short* __restrict__ col16,
                                                   unsigned short* __restrict__ zb,
                                                   int n) {
    __shared__ __align__(16) char smemc[sizeof(SmemCSR)];
    SmemCSR* s = (SmemCSR*)smemc;
    int t = threadIdx.x;
    int b = blockIdx.x;
    int node0 = b << 8;
    int nn = n - node0;
    if (nn > 256) nn = 256;
    if (nn < 0) nn = 0;
    int e0 = b * CAPB;            // bpacked segment
    int e0c = b * CAPC;           // col16 (padded) segment
    int ne = bcurP[b * 16];
    s->cnt[t] = 0;
    __syncthreads();
    int n4 = (ne + 3) >> 2;
    for (int i = t; i < n4; i += 256) {
        uint4 v = *(const uint4*)&bpacked[e0 + 4 * i];
        int rem = ne - 4 * i;
        if (rem > 0) atomicAdd(&s->cnt[(v.x >> 16) & 255u], 1);
        if (rem > 1) atomicAdd(&s->cnt[(v.y >> 16) & 255u], 1);
        if (rem > 2) atomicAdd(&s->cnt[(v.z >> 16) & 255u], 1);
        if (rem > 3) atomicAdd(&s->cnt[(v.w >> 16) & 255u], 1);
    }
    __syncthreads();
    int c = s->cnt[t];
    // group-of-4 max, rounded up to multiple of 8 -> padded length P
    int gm = max(c, __shfl_xor(c, 1));
    gm = max(gm, __shfl_xor(gm, 2));
    int P = (gm + 7) & ~7;
    s->sA[t] = P;
    __syncthreads();
    for (int off = 1; off < NBKT; off <<= 1) {
        int v = (t >= off) ? s->sA[t - off] : 0;
        __syncthreads();
        s->sA[t] += v;
        __syncthreads();
    }
    int excl = s->sA[t] - P;
    s->cur[t] = excl;
    float dv = rsqrtf((float)(c + 1));
    s->disL[t] = dv;
    if (t < nn) {
        row_ptr[node0 + t] = e0c + excl;
        degA[node0 + t] = P;                      // padded length
        dis[node0 + t] = dv;                      // real degree scale
    }
    __syncthreads();
    int totP = s->sA[NBKT - 1];
    // sentinel-init the whole padded region (index n -> zero row)
    unsigned short sent = (unsigned short)n;
    for (int i = t; i < totP; i += 256) s->stage[i] = sent;
    __syncthreads();
    for (int i = t; i < n4; i += 256) {
        uint4 v = *(const uint4*)&bpacked[e0 + 4 * i];
        int rem = ne - 4 * i;
        unsigned vv[4] = {v.x, v.y, v.z, v.w};
        #pragma unroll
        for (int j = 0; j < 4; ++j) {
            if (rem > j) {
                int ld = (int)((vv[j] >> 16) & 255u);
                int p = atomicAdd(&s->cur[ld], 1);
                s->stage[p] = (unsigned short)(vv[j] & 0xFFFFu);
            }
        }
    }
    __syncthreads();
    // coalesced flush of the whole padded segment (2 ushort per uint store)
    int nw = totP >> 1;   // totP is a multiple of 8
    for (int i = t; i < nw; i += 256) {
        unsigned w = (unsigned)s->stage[2 * i] | ((unsigned)s->stage[2 * i + 1] << 16);
        *(unsigned*)&col16[e0c + 2 * i] = w;
    }
    // fused pre-scale of zb rows owned by this bucket
    for (int idx = t; idx < nn * 16; idx += 256) {
        int r = idx >> 4;
        int c8 = (idx & 15) * 8;
        float sc = s->disL[r];
        size_t o8 = (size_t)(node0 + r) * 128 + c8;
        uint4 v = *(const uint4*)&zb[o8];
        unsigned* w = (unsigned*)&v;
        #pragma unroll
        for (int k2 = 0; k2 < 4; ++k2) {
            float2 f = unpack_bf2(w[k2]);
            w[k2] = pack_bf2(f.x * sc, f.y * sc);
        }
        *(uint4*)&zb[o8] = v;
    }
}

// =============== gather core: 16 lanes/node, 8-edge tiles, shuffle indices ===============
// Fully UNCONDITIONAL gather: segments are sentinel-padded (index n -> zeroed
// row), so there is no bounds predication on idx loads, row loads, or consume.
// R4-proven 2-buffer pipeline + pk_add_f32 consume. VGPR < 64 (8 w/SIMD).

__device__ __forceinline__ void consume8(const uint4* v, f32x2* acc) {
    #pragma unroll
    for (int j = 0; j < 8; ++j) {
        const unsigned* w = (const unsigned*)&v[j];
        #pragma unroll
        for (int i2 = 0; i2 < 4; ++i2)
            acc[i2] += bf2_to_f32x2(w[i2]);
    }
}

__device__ __forceinline__ void issue8(const unsigned short* __restrict__ hws,
                                       int sl, int lsel, int creg, uint4* v) {
    #pragma unroll
    for (int j = 0; j < 8; ++j) {
        int s = __shfl(creg, lsel + j);
        v[j] = *(const uint4*)(hws + ((size_t)s << 7) + (sl << 3));
    }
}

__device__ __forceinline__ void gather_pipe(const unsigned short* __restrict__ hws,
                                            const unsigned short* __restrict__ col16,
                                            int e0, int P, int sl, int part,
                                            f32x2* acc) {
    int nt = P >> 3;
    if (nt <= 0) return;
    int base = part << 4;
    uint4 vA[8], vB[8];
    int c0 = (int)col16[e0 + sl];
    int c1 = (int)col16[e0 + 16 + sl];
    int n0 = 0, n1 = 0;

    issue8(hws, sl, base, c0, vA);      // tile 0
    int t = 0, ebase = 0;
    for (;;) {
        // ---- phase0: tile t (==0 mod 4) in vA ----
        if (t + 4 < nt) {   // prefetch next macro's indices FIRST (oldest for counted wait)
            n0 = (int)col16[e0 + ebase + 32 + sl];
            n1 = (int)col16[e0 + ebase + 48 + sl];
        }
        if (t + 1 < nt) issue8(hws, sl, base + 8, c0, vB);
        consume8(vA, acc);
        if (++t >= nt) break;
        // ---- phase1: tile t in vB ----
        if (t + 1 < nt) issue8(hws, sl, base, c1, vA);
        consume8(vB, acc);
        if (++t >= nt) break;
        // ---- phase2: tile t in vA ----
        if (t + 1 < nt) issue8(hws, sl, base + 8, c1, vB);
        consume8(vA, acc);
        if (++t >= nt) break;
        // ---- phase3: tile t in vB; next tile uses the prefetched n0 ----
        if (t + 1 < nt) issue8(hws, sl, base, n0, vA);
        consume8(vB, acc);
        if (++t >= nt) break;
        c0 = n0; c1 = n1; ebase += 32;
    }
}

// ------- FUSED: layer-1 agg (unscaled gather of pre-scaled zb) + BN + ReLU
//         -> h1 (LDS) -> GEMM2 -> hws2 (pre-scaled) -------

__global__ __launch_bounds__(256, 3) void k_agg1_gemm2(const unsigned short* __restrict__ zb,
                                                       const int* __restrict__ row_ptr,
                                                       const int* __restrict__ degA,
                                                       const unsigned short* __restrict__ col16,
                                                       const float* __restrict__ dis,
                                                       const float* __restrict__ bias,
                                                       const float* __restrict__ gamma,
                                                       const float* __restrict__ beta,
                                                       const float* __restrict__ mean,
                                                       const float* __restrict__ var,
                                                       const unsigned short* __restrict__ wt2,
                                                       unsigned short* __restrict__ hwsb2, int n) {
    __shared__ unsigned short H1[16][ASTR];
    __shared__ unsigned short C2[16][ASTR];
    int t = threadIdx.x;
    int wave = t >> 6, lane = t & 63;
    int sl = lane & 15, part = lane >> 4;
    int d = blockIdx.x * 16 + wave * 4 + part;
    bool active = (d < n);
    int e0 = 0, P = 0;
    if (active) {
        e0 = row_ptr[d];
        P = degA[d];     // padded length, uniform across the group of 4
    }
    // preload self row + self dis BEFORE the gather: oldest in flight, retire free
    uint4 vs = make_uint4(0, 0, 0, 0);
    float dd = 0.f;
    if (active) {
        vs = *(const uint4*)(zb + ((size_t)d << 7) + (sl << 3));
        dd = dis[d];
    }
    int md = P;
    md = max(md, __shfl_xor(md, 16));
    md = max(md, __shfl_xor(md, 32));

    f32x2 acc[4];
    #pragma unroll
    for (int i = 0; i < 4; ++i) acc[i] = (f32x2){0.f, 0.f};
    gather_pipe(zb, col16, e0, md, sl, part, acc);

    unsigned outw[4] = {0, 0, 0, 0};
    if (active) {
        const unsigned* w = (const unsigned*)&vs;
        #pragma unroll
        for (int i2 = 0; i2 < 4; ++i2)
            acc[i2] += bf2_to_f32x2(w[i2]);   // zb pre-scaled: self term is zs[d]
        int f0 = sl << 3;
        #pragma unroll
        for (int i2 = 0; i2 < 4; ++i2) {
            int f = f0 + 2 * i2;
            float2 bv = *(const float2*)&bias[f];
            float2 gm = *(const float2*)&gamma[f];
            float2 bt = *(const float2*)&beta[f];
            float2 mn = *(const float2*)&mean[f];
            float2 vr = *(const float2*)&var[f];
            float vx = acc[i2].x * dd + bv.x;
            float vy = acc[i2].y * dd + bv.y;
            float sx = gm.x * rsqrtf(vr.x + BN_EPS);
            float sy = gm.y * rsqrtf(vr.y + BN_EPS);
            float rx = fmaxf((vx - mn.x) * sx + bt.x, 0.f);
            float ry = fmaxf((vy - mn.y) * sy + bt.y, 0.f);
            outw[i2] = pack_bf2(rx, ry);
        }
    }
    int local = wave * 4 + part;
    *(uint4*)&H1[local][sl << 3] = *(uint4*)outw;
    __syncthreads();

    int m = sl;
    int quad = part;
    short8 a2[4];
    #pragma unroll
    for (int kt = 0; kt < 4; ++kt)
        a2[kt] = *(const short8*)&H1[m][kt * 32 + quad * 8];

    f32x4 acc2[2];
    acc2[0] = (f32x4){0.f, 0.f, 0.f, 0.f};
    acc2[1] = (f32x4){0.f, 0.f, 0.f, 0.f};
    #pragma unroll
    for (int i = 0; i < 2; ++i) {
        int ct = wave * 2 + i;
        const unsigned short* wb = &wt2[(size_t)(ct * 16 + m) * 128 + quad * 8];
        #pragma unroll
        for (int kt = 0; kt < 4; ++kt) {
            short8 b = *(const short8*)(wb + kt * 32);
            acc2[i] = __builtin_amdgcn_mfma_f32_16x16x32_bf16(a2[kt], b, acc2[i], 0, 0, 0);
        }
    }
    int gr = blockIdx.x * 16 + quad * 4;
    float ds2[4];
    #pragma unroll
    for (int reg = 0; reg < 4; ++reg)
        ds2[reg] = (gr + reg < n) ? dis[gr + reg] : 0.f;
    #pragma unroll
    for (int i = 0; i < 2; ++i) {
        int col = (wave * 2 + i) * 16 + m;
        #pragma unroll
        for (int reg = 0; reg < 4; ++reg)
            C2[quad * 4 + reg][col] = bf16_1(acc2[i][reg] * ds2[reg]);
    }
    __syncthreads();
    {
        int r = t >> 4;
        int c8 = (t & 15) * 8;
        int grow = blockIdx.x * 16 + r;
        if (grow < n)
            *(uint4*)&hwsb2[(size_t)grow * 128 + c8] = *(const uint4*)&C2[r][c8];
    }
}

// ------- layer-2 agg + BN + ReLU + attention + logits; block=256, 16 nodes -------

__global__ __launch_bounds__(256, 3) void k_agg2_att_logit(const unsigned short* __restrict__ hwsb,
                                                           const int* __restrict__ row_ptr,
                                                           const int* __restrict__ degA,
                                                           const unsigned short* __restrict__ col16,
                                                           const float* __restrict__ dis,
                                                           const float* __restrict__ bias,
                                                           const float* __restrict__ gamma,
                                                           const float* __restrict__ beta,
                                                           const float* __restrict__ mean,
                                                           const float* __restrict__ var,
                                                           const int* __restrict__ batch,
                                                           const float* __restrict__ att_w,
                                                           const float* __restrict__ cls_w,
                                                           float* __restrict__ att_out,
                                                           float* __restrict__ logits, int n) {
    __shared__ int   sg[16];
    __shared__ float sv[16];
    int t = threadIdx.x;
    int wave = t >> 6, lane = t & 63;
    int sl = lane & 15, part = lane >> 4;
    int d = blockIdx.x * 16 + wave * 4 + part;
    bool active = (d < n);
    int e0 = 0, P = 0;
    if (active) {
        e0 = row_ptr[d];
        P = degA[d];
    }
    // preload self row, self dis, and batch id BEFORE the gather
    uint4 vs = make_uint4(0, 0, 0, 0);
    float dd = 0.f;
    int g = -1;
    if (active) {
        vs = *(const uint4*)(hwsb + ((size_t)d << 7) + (sl << 3));
        dd = dis[d];
        g = batch[d];
    }
    int md = P;
    md = max(md, __shfl_xor(md, 16));
    md = max(md, __shfl_xor(md, 32));

    f32x2 acc[4];
    #pragma unroll
    for (int i = 0; i < 4; ++i) acc[i] = (f32x2){0.f, 0.f};
    gather_pipe(hwsb, col16, e0, md, sl, part, acc);

    float contrib = 0.f;
    float p = 0.f, q = 0.f;
    if (active) {
        const unsigned* w = (const unsigned*)&vs;
        #pragma unroll
        for (int i2 = 0; i2 < 4; ++i2)
            acc[i2] += bf2_to_f32x2(w[i2]);
        float dd2 = dd;
        int f0 = sl << 3;
        #pragma unroll
        for (int i2 = 0; i2 < 4; ++i2) {
            int f = f0 + 2 * i2;
            float2 bv = *(const float2*)&bias[f];
            float2 gm = *(const float2*)&gamma[f];
            float2 bt = *(const float2*)&beta[f];
            float2 mn = *(const float2*)&mean[f];
            float2 vr = *(const float2*)&var[f];
            float vx = acc[i2].x * dd2 + bv.x;
            float vy = acc[i2].y * dd2 + bv.y;
            float sx = gm.x * rsqrtf(vr.x + BN_EPS);
            float sy = gm.y * rsqrtf(vr.y + BN_EPS);
            float rx = fmaxf((vx - mn.x) * sx + bt.x, 0.f);
            float ry = fmaxf((vy - mn.y) * sy + bt.y, 0.f);
            float2 aw = *(const float2*)&att_w[f];
            float2 cw = *(const float2*)&cls_w[f];
            p += rx * aw.x + ry * aw.y;
            q += rx * cw.x + ry * cw.y;
        }
    }
    #pragma unroll
    for (int off = 1; off < 16; off <<= 1) {
        p += __shfl_xor(p, off);
        q += __shfl_xor(q, off);
    }
    if (active) {
        float a = 1.f / (1.f + expf(-p));
        if (sl == 0) att_out[d] = a;
        contrib = a * q;
    }
    if (sl == 0) {
        sg[wave * 4 + part] = g;
        sv[wave * 4 + part] = contrib;
    }
    __syncthreads();
    if (t == 0) {
        int cur = -1;
        float acc2 = 0.f;
        #pragma unroll
        for (int i = 0; i < 16; ++i) {
            int gi = sg[i];
            if (gi < 0) continue;
            if (gi != cur) {
                if (cur >= 0) atomicAdd(&logits[cur], acc2);
                cur = gi;
                acc2 = 0.f;
            }
            acc2 += sv[i];
        }
        if (cur >= 0) atomicAdd(&logits[cur], acc2);
    }
}

// ---------------- launch ----------------

extern "C" void kernel_launch(void* const* d_in, const int* in_sizes, int n_in,
                              void* d_out, int out_size, void* d_ws, size_t ws_size,
                              hipStream_t stream) {
    const float* x   = (const float*)d_in[0];
    const int*   ei  = (const int*)d_in[1];
    const int*   bat = (const int*)d_in[2];
    const float* W1  = (const float*)d_in[3];
    const float* b1  = (const float*)d_in[4];
    const float* g1  = (const float*)d_in[5];
    const float* bt1 = (const float*)d_in[6];
    const float* mn1 = (const float*)d_in[7];
    const float* vr1 = (const float*)d_in[8];
    const float* W2  = (const float*)d_in[9];
    const float* b2  = (const float*)d_in[10];
    const float* g2  = (const float*)d_in[11];
    const float* bt2 = (const float*)d_in[12];
    const float* mn2 = (const float*)d_in[13];
    const float* vr2 = (const float*)d_in[14];
    const float* attw = (const float*)d_in[15];
    const float* clsw = (const float*)d_in[16];
    const float* clsb = (const float*)d_in[17];

    int E = in_sizes[1] / 2;
    int n = in_sizes[2];
    const int* src = ei;
    const int* dst = ei + E;
    int NB = (n + 255) >> 8;       // buckets of 256 nodes

    char* ws = (char*)d_ws;
    auto alloc = [&](size_t bytes) {
        void* p = (void*)ws;
        ws += (bytes + 255) & ~(size_t)255;
        return p;
    };
    int*            bcurP   = (int*)alloc(NBKT * 16 * 4);
    unsigned*       bpacked = (unsigned*)alloc((size_t)NBKT * CAPB * 4);
    int*            row_ptr = (int*)alloc((size_t)n * 4);
    int*            degA    = (int*)alloc((size_t)n * 4);
    unsigned short* col16   = (unsigned short*)alloc(((size_t)NBKT * CAPC + 1024) * 2);
    float*          dis     = (float*)alloc((size_t)n * 4);
    unsigned short* zb      = (unsigned short*)alloc((size_t)(n + 1) * 128 * 2);
    unsigned short* hwsb2   = (unsigned short*)alloc((size_t)(n + 1) * 128 * 2);
    unsigned short* wt1     = (unsigned short*)alloc(128 * 128 * 2);
    unsigned short* wt2     = (unsigned short*)alloc(128 * 128 * 2);

    float* out = (float*)d_out;
    int DB = (E + ETILE - 1) / ETILE;
    int gb = (n + 63) / 64;        // ALL gemm1 tiles ride with distribute
    int ab = (n + 15) / 16;

    k_prep0<<<3, 256, 0, stream>>>(W1, W2, wt1, wt2, bcurP, clsb, out, zb, hwsb2, n);
    k_dist_gemm1<<<DB + gb, 256, 0, stream>>>(src, dst, bcurP, bpacked, x, wt1, zb,
                                              E, n, DB);
    k_csr_scale<<<NB, 256, 0, stream>>>(bpacked, bcurP, row_ptr, degA, dis,
                                        col16, zb, n);
    k_agg1_gemm2<<<ab, 256, 0, stream>>>(zb, row_ptr, degA, col16, dis,
                                         b1, g1, bt1, mn1, vr1, wt2, hwsb2, n);
    k_agg2_att_logit<<<ab, 256, 0, stream>>>(hwsb2, row_ptr, degA, col16, dis,
                                             b2, g2, bt2, mn2, vr2, bat, attw, clsw,
                                             out + NG, out, n);
}

// Round 13
// 253.224 us; speedup vs baseline: 1.0777x; 1.0045x over previous
//
#include <hip/hip_runtime.h>
#include <math.h>

#define NN 50000
#define HID 128
#define NG 64
#define BN_EPS 1e-5f

typedef __attribute__((ext_vector_type(8))) short short8;
typedef __attribute__((ext_vector_type(4))) float f32x4;
typedef __attribute__((ext_vector_type(2))) float f32x2;

// ---- bf16 pack/unpack (RNE) ----
__device__ inline unsigned pack_bf2(float a, float b) {
    union { float f; unsigned u; } ua, ub;
    ua.f = a; ub.f = b;
    unsigned x = ua.u, y = ub.u;
    x += 0x7fffu + ((x >> 16) & 1u);
    y += 0x7fffu + ((y >> 16) & 1u);
    return (x >> 16) | (y & 0xffff0000u);
}
__device__ inline unsigned short bf16_1(float x) {
    union { float f; unsigned u; } v;
    v.f = x;
    unsigned r = v.u + 0x7fffu + ((v.u >> 16) & 1u);
    return (unsigned short)(r >> 16);
}
__device__ inline float2 unpack_bf2(unsigned v) {
    union { unsigned u; float f; } a, b;
    a.u = v << 16;
    b.u = v & 0xffff0000u;
    return make_float2(a.f, b.f);
}
// bf16-pair -> f32x2 (for packed v_pk_add_f32 accumulation)
__device__ __forceinline__ f32x2 bf2_to_f32x2(unsigned u) {
    union { unsigned q; float f; } a, b;
    a.q = u << 16;
    b.q = u & 0xffff0000u;
    f32x2 r;
    r.x = a.f;
    r.y = b.f;
    return r;
}

// =============== CSR build — fixed-capacity buckets ===============
// K = 256 nodes/bucket (pow2). R8's atomic-cursor split-fused form. Group-of-4
// node segments in col16 PADDED to multiple-of-8 with sentinel index n (zeroed
// row in zb/hwsb2) so the agg gather is fully unconditional (R11).
// R13: the csr launch is split into SORT blocks [0,NB) and SCALE blocks
// [NB,2NB) — the zb pre-scale only needs the degree histogram, so it runs as
// independent blocks, doubling the launch's parallelism (196 -> 392 blocks on
// 256 CUs) and shortening the serial per-block chain.
#define NBKT 256                 // scan width (buckets used = NB <= 256)
#define ETILE 4096
#define EPT   (ETILE / 256)      // 16 edges per thread
#define CAPB  10240              // bpacked: avg bucket load 8192; +25% headroom
#define CAPC  12800              // col16 (padded): avg ~10900; +17% headroom
#define ASTR 136

// prep: blocks 0,1 = LDS-staged coalesced W transpose; block 2 = cursors +
// logits seed + sentinel rows of zb/hwsb2.
__global__ __launch_bounds__(256) void k_prep0(const float* __restrict__ W1,
                                               const float* __restrict__ W2,
                                               unsigned short* __restrict__ wt1,
                                               unsigned short* __restrict__ wt2,
                                               int* __restrict__ bcurP,
                                               const float* __restrict__ cls_b,
                                               float* __restrict__ logits,
                                               unsigned short* __restrict__ zb,
                                               unsigned short* __restrict__ hwsb2,
                                               int n) {
    int b = blockIdx.x;
    int t = threadIdx.x;
    if (b < 2) {
        __shared__ unsigned short T[128][130];
        const float* W = b ? W2 : W1;
        unsigned short* wt = b ? wt2 : wt1;
        #pragma unroll
        for (int i = 0; i < 64; ++i) {
            int idx = i * 256 + t;
            int r = idx >> 7, c = idx & 127;
            T[c][r] = bf16_1(W[r * 128 + c]);   // coalesced read; LDS scatter
        }
        __syncthreads();
        #pragma unroll
        for (int i = 0; i < 32; ++i) {
            int idx = i * 256 + t;              // uint index, 8192 total
            int r = idx >> 6, c2 = (idx & 63) * 2;
            unsigned w = (unsigned)T[r][c2] | ((unsigned)T[r][c2 + 1] << 16);
            *(unsigned*)&wt[r * 128 + c2] = w;  // coalesced 4B writes
        }
    } else {
        #pragma unroll
        for (int i = 0; i < 16; ++i) bcurP[t * 16 + i] = 0;
        if (t < NG) logits[t] = cls_b[0];
        if (t < 64) *(unsigned*)((char*)zb + (size_t)n * 256 + t * 4) = 0u;
        else if (t < 128) *(unsigned*)((char*)hwsb2 + (size_t)n * 256 + (t - 64) * 4) = 0u;
    }
}

// ---- shared gemm1 tile body: z[row0..row0+64) = bf16(x@W1), UNSCALED ----
__device__ __forceinline__ void gemm1_tile(char* smem, int row0,
                                           const float* __restrict__ x,
                                           const unsigned short* __restrict__ wt1,
                                           unsigned short* __restrict__ zb,
                                           int n, int t) {
    typedef unsigned short ArowT[ASTR];
    ArowT* A = (ArowT*)smem;
    #pragma unroll
    for (int i = 0; i < 8; ++i) {
        int idx = t + i * 256;
        int r = idx >> 5;
        int c4 = (idx & 31) * 4;
        float4 v = make_float4(0.f, 0.f, 0.f, 0.f);
        if (row0 + r < n) v = *(const float4*)&x[(size_t)(row0 + r) * 128 + c4];
        uint2 p;
        p.x = pack_bf2(v.x, v.y);
        p.y = pack_bf2(v.z, v.w);
        *(uint2*)&A[r][c4] = p;
    }
    __syncthreads();
    int lane = t & 63;
    int wave = t >> 6;
    int m = lane & 15;
    int quad = lane >> 4;
    int r0 = wave * 16;
    short8 a[4];
    #pragma unroll
    for (int kt = 0; kt < 4; ++kt)
        a[kt] = *(const short8*)&A[r0 + m][kt * 32 + quad * 8];
    f32x4 acc[8];
    #pragma unroll
    for (int ct = 0; ct < 8; ++ct) acc[ct] = (f32x4){0.f, 0.f, 0.f, 0.f};
    short8 bcur[4], bnxt[4];
    {
        const unsigned short* wb = &wt1[(size_t)m * 128 + quad * 8];
        #pragma unroll
        for (int kt = 0; kt < 4; ++kt) bcur[kt] = *(const short8*)(wb + kt * 32);
    }
    #pragma unroll
    for (int ct = 0; ct < 8; ++ct) {
        if (ct < 7) {
            const unsigned short* wb = &wt1[(size_t)((ct + 1) * 16 + m) * 128 + quad * 8];
            #pragma unroll
            for (int kt = 0; kt < 4; ++kt) bnxt[kt] = *(const short8*)(wb + kt * 32);
        }
        #pragma unroll
        for (int kt = 0; kt < 4; ++kt)
            acc[ct] = __builtin_amdgcn_mfma_f32_16x16x32_bf16(a[kt], bcur[kt], acc[ct], 0, 0, 0);
        #pragma unroll
        for (int kt = 0; kt < 4; ++kt) bcur[kt] = bnxt[kt];
    }
    __syncthreads();
    #pragma unroll
    for (int ct = 0; ct < 8; ++ct) {
        int col = ct * 16 + m;
        #pragma unroll
        for (int reg = 0; reg < 4; ++reg)
            A[r0 + quad * 4 + reg][col] = bf16_1(acc[ct][reg]);
    }
    __syncthreads();
    #pragma unroll
    for (int i = 0; i < 4; ++i) {
        int idx = t + i * 256;
        int r = idx >> 4;
        int c8 = (idx & 15) * 8;
        int grow = row0 + r;
        if (grow < n)
            *(uint4*)&zb[(size_t)grow * 128 + c8] = *(const uint4*)&A[r][c8];
    }
}

// L2a: blocks [0,DB) = edge distribute (coalesced LDS counting sort);
//      blocks [DB,..) = ALL gemm1 tiles (zb fully written by end of launch).
struct SmemDist {
    int h[NBKT], sx[NBKT], cur[NBKT], gb[NBKT];
    unsigned stage[ETILE];
};

__global__ __launch_bounds__(256) void k_dist_gemm1(const int* __restrict__ src,
                                                    const int* __restrict__ dst,
                                                    int* __restrict__ bcurP,
                                                    unsigned* __restrict__ bpacked,
                                                    const float* __restrict__ x,
                                                    const unsigned short* __restrict__ wt1,
                                                    unsigned short* __restrict__ zb,
                                                    int E, int n, int DB) {
    __shared__ __align__(16) char smem[sizeof(SmemDist)];
    int t = threadIdx.x;
    int b = blockIdx.x;

    if (b >= DB) {
        gemm1_tile(smem, (b - DB) * 64, x, wt1, zb, n, t);
        return;
    }
    // ---------------- distribute path ----------------
    SmemDist* s = (SmemDist*)smem;
    s->h[t] = 0;
    __syncthreads();
    int base = b * ETILE;
    int dreg[EPT];
    #pragma unroll
    for (int i = 0; i < EPT; ++i) {
        int e = base + i * 256 + t;
        dreg[i] = (e < E) ? dst[e] : -1;
        if (dreg[i] >= 0) atomicAdd(&s->h[dreg[i] >> 8], 1);
    }
    __syncthreads();
    int c = s->h[t];
    s->sx[t] = c;
    __syncthreads();
    for (int off = 1; off < NBKT; off <<= 1) {
        int v = (t >= off) ? s->sx[t - off] : 0;
        __syncthreads();
        s->sx[t] += v;
        __syncthreads();
    }
    int nvalid = s->sx[NBKT - 1];
    int excl = s->sx[t] - c;
    __syncthreads();
    s->sx[t] = excl;
    s->cur[t] = excl;
    s->gb[t] = (c > 0) ? atomicAdd(&bcurP[t * 16], c) : 0;
    __syncthreads();
    #pragma unroll
    for (int i = 0; i < EPT; ++i) {
        int e = base + i * 256 + t;
        if (dreg[i] >= 0) {
            int d = dreg[i];
            int bkt = d >> 8;
            int p = atomicAdd(&s->cur[bkt], 1);
            s->stage[p] = ((unsigned)d << 16) | (unsigned)src[e];
        }
    }
    __syncthreads();
    for (int idx = t; idx < nvalid; idx += 256) {
        unsigned v = s->stage[idx];
        int bkt = (int)(v >> 24);
        int pos = s->gb[bkt] + (idx - s->sx[bkt]);
        bpacked[(size_t)bkt * CAPB + pos] = v;
    }
}

// L2b, dual-role launch (grid = 2*NB):
//  blocks [0,NB): bucket CSR counting sort with GROUP-OF-4 PADDING (ushort
//   col16, sentinel gaps, LDS-staged coalesced writes). Writes row_ptr (padded
//   offsets), degA (padded length), col16.
//  blocks [NB,2NB): independent histogram-only pass -> dis = rsqrt(deg+1) +
//   zb pre-scale for this bucket's 256 nodes. (Scale needs only the degree
//   histogram, not the sort — so it runs in parallel with the sort blocks.)
struct SmemCSR {
    int cnt[NBKT], sA[NBKT], cur[NBKT];
    unsigned short stage[CAPC];
};

__global__ __launch_bounds__(256) void k_csr_scale(const unsigned* __restrict__ bpacked,
                                                   const int* __restrict__ bcurP,
                                                   int* __restrict__ row_ptr,
                                                   int* __restrict__ degA,
                                                   float* __restrict__ dis,
                                                   unsigned short* __restrict__ col16,
                                                   unsigned short* __restrict__ zb,
                                                   int n, int NB) {
    __shared__ __align__(16) char smemc[sizeof(SmemCSR)];
    SmemCSR* s = (SmemCSR*)smemc;
    int t = threadIdx.x;
    int b = blockIdx.x;
    bool scale_role = (b >= NB);
    if (scale_role) b -= NB;
    int node0 = b << 8;
    int nn = n - node0;
    if (nn > 256) nn = 256;
    if (nn < 0) nn = 0;
    int e0 = b * CAPB;            // bpacked segment
    int ne = bcurP[b * 16];
    s->cnt[t] = 0;
    __syncthreads();
    int n4 = (ne + 3) >> 2;
    for (int i = t; i < n4; i += 256) {
        uint4 v = *(const uint4*)&bpacked[e0 + 4 * i];
        int rem = ne - 4 * i;
        if (rem > 0) atomicAdd(&s->cnt[(v.x >> 16) & 255u], 1);
        if (rem > 1) atomicAdd(&s->cnt[(v.y >> 16) & 255u], 1);
        if (rem > 2) atomicAdd(&s->cnt[(v.z >> 16) & 255u], 1);
        if (rem > 3) atomicAdd(&s->cnt[(v.w >> 16) & 255u], 1);
    }
    __syncthreads();
    int c = s->cnt[t];

    if (scale_role) {
        // ---------- dis + zb pre-scale ----------
        float dv = rsqrtf((float)(c + 1));
        __syncthreads();
        ((float*)s->cnt)[t] = dv;     // reuse cnt[] as disL[]
        if (t < nn) dis[node0 + t] = dv;
        __syncthreads();
        const float* disL = (const float*)s->cnt;
        for (int idx = t; idx < nn * 16; idx += 256) {
            int r = idx >> 4;
            int c8 = (idx & 15) * 8;
            float sc = disL[r];
            size_t o8 = (size_t)(node0 + r) * 128 + c8;
            uint4 v = *(const uint4*)&zb[o8];
            unsigned* w = (unsigned*)&v;
            #pragma unroll
            for (int k2 = 0; k2 < 4; ++k2) {
                float2 f = unpack_bf2(w[k2]);
                w[k2] = pack_bf2(f.x * sc, f.y * sc);
            }
            *(uint4*)&zb[o8] = v;
        }
        return;
    }

    // ---------- counting sort + padded col16 flush ----------
    int e0c = b * CAPC;           // col16 (padded) segment
    // group-of-4 max, rounded up to multiple of 8 -> padded length P
    int gm = max(c, __shfl_xor(c, 1));
    gm = max(gm, __shfl_xor(gm, 2));
    int P = (gm + 7) & ~7;
    s->sA[t] = P;
    __syncthreads();
    for (int off = 1; off < NBKT; off <<= 1) {
        int v = (t >= off) ? s->sA[t - off] : 0;
        __syncthreads();
        s->sA[t] += v;
        __syncthreads();
    }
    int excl = s->sA[t] - P;
    s->cur[t] = excl;
    if (t < nn) {
        row_ptr[node0 + t] = e0c + excl;
        degA[node0 + t] = P;                      // padded length
    }
    __syncthreads();
    int totP = s->sA[NBKT - 1];
    // sentinel-init the whole padded region (index n -> zero row)
    unsigned short sent = (unsigned short)n;
    for (int i = t; i < totP; i += 256) s->stage[i] = sent;
    __syncthreads();
    for (int i = t; i < n4; i += 256) {
        uint4 v = *(const uint4*)&bpacked[e0 + 4 * i];
        int rem = ne - 4 * i;
        unsigned vv[4] = {v.x, v.y, v.z, v.w};
        #pragma unroll
        for (int j = 0; j < 4; ++j) {
            if (rem > j) {
                int ld = (int)((vv[j] >> 16) & 255u);
                int p = atomicAdd(&s->cur[ld], 1);
                s->stage[p] = (unsigned short)(vv[j] & 0xFFFFu);
            }
        }
    }
    __syncthreads();
    // coalesced flush of the whole padded segment (2 ushort per uint store)
    int nw = totP >> 1;   // totP is a multiple of 8
    for (int i = t; i < nw; i += 256) {
        unsigned w = (unsigned)s->stage[2 * i] | ((unsigned)s->stage[2 * i + 1] << 16);
        *(unsigned*)&col16[e0c + 2 * i] = w;
    }
}

// =============== gather core: 16 lanes/node, 8-edge tiles, shuffle indices ===============
// Fully UNCONDITIONAL gather: segments are sentinel-padded (index n -> zeroed
// row), so there is no bounds predication on idx loads, row loads, or consume.
// R4-proven 2-buffer pipeline + pk_add_f32 consume. VGPR < 64 (8 w/SIMD).

__device__ __forceinline__ void consume8(const uint4* v, f32x2* acc) {
    #pragma unroll
    for (int j = 0; j < 8; ++j) {
        const unsigned* w = (const unsigned*)&v[j];
        #pragma unroll
        for (int i2 = 0; i2 < 4; ++i2)
            acc[i2] += bf2_to_f32x2(w[i2]);
    }
}

__device__ __forceinline__ void issue8(const unsigned short* __restrict__ hws,
                                       int sl, int lsel, int creg, uint4* v) {
    #pragma unroll
    for (int j = 0; j < 8; ++j) {
        int s = __shfl(creg, lsel + j);
        v[j] = *(const uint4*)(hws + ((size_t)s << 7) + (sl << 3));
    }
}

__device__ __forceinline__ void gather_pipe(const unsigned short* __restrict__ hws,
                                            const unsigned short* __restrict__ col16,
                                            int e0, int P, int sl, int part,
                                            f32x2* acc) {
    int nt = P >> 3;
    if (nt <= 0) return;
    int base = part << 4;
    uint4 vA[8], vB[8];
    int c0 = (int)col16[e0 + sl];
    int c1 = (int)col16[e0 + 16 + sl];
    int n0 = 0, n1 = 0;

    issue8(hws, sl, base, c0, vA);      // tile 0
    int t = 0, ebase = 0;
    for (;;) {
        // ---- phase0: tile t (==0 mod 4) in vA ----
        if (t + 4 < nt) {   // prefetch next macro's indices FIRST (oldest for counted wait)
            n0 = (int)col16[e0 + ebase + 32 + sl];
            n1 = (int)col16[e0 + ebase + 48 + sl];
        }
        if (t + 1 < nt) issue8(hws, sl, base + 8, c0, vB);
        consume8(vA, acc);
        if (++t >= nt) break;
        // ---- phase1: tile t in vB ----
        if (t + 1 < nt) issue8(hws, sl, base, c1, vA);
        consume8(vB, acc);
        if (++t >= nt) break;
        // ---- phase2: tile t in vA ----
        if (t + 1 < nt) issue8(hws, sl, base + 8, c1, vB);
        consume8(vA, acc);
        if (++t >= nt) break;
        // ---- phase3: tile t in vB; next tile uses the prefetched n0 ----
        if (t + 1 < nt) issue8(hws, sl, base, n0, vA);
        consume8(vB, acc);
        if (++t >= nt) break;
        c0 = n0; c1 = n1; ebase += 32;
    }
}

// ------- FUSED: layer-1 agg (unscaled gather of pre-scaled zb) + BN + ReLU
//         -> h1 (LDS) -> GEMM2 -> hws2 (pre-scaled) -------

__global__ __launch_bounds__(256, 3) void k_agg1_gemm2(const unsigned short* __restrict__ zb,
                                                       const int* __restrict__ row_ptr,
                                                       const int* __restrict__ degA,
                                                       const unsigned short* __restrict__ col16,
                                                       const float* __restrict__ dis,
                                                       const float* __restrict__ bias,
                                                       const float* __restrict__ gamma,
                                                       const float* __restrict__ beta,
                                                       const float* __restrict__ mean,
                                                       const float* __restrict__ var,
                                                       const unsigned short* __restrict__ wt2,
                                                       unsigned short* __restrict__ hwsb2, int n) {
    __shared__ unsigned short H1[16][ASTR];
    __shared__ unsigned short C2[16][ASTR];
    int t = threadIdx.x;
    int wave = t >> 6, lane = t & 63;
    int sl = lane & 15, part = lane >> 4;
    int d = blockIdx.x * 16 + wave * 4 + part;
    bool active = (d < n);
    int e0 = 0, P = 0;
    if (active) {
        e0 = row_ptr[d];
        P = degA[d];     // padded length, uniform across the group of 4
    }
    // preload self row + self dis BEFORE the gather: oldest in flight, retire free
    uint4 vs = make_uint4(0, 0, 0, 0);
    float dd = 0.f;
    if (active) {
        vs = *(const uint4*)(zb + ((size_t)d << 7) + (sl << 3));
        dd = dis[d];
    }
    int md = P;
    md = max(md, __shfl_xor(md, 16));
    md = max(md, __shfl_xor(md, 32));

    f32x2 acc[4];
    #pragma unroll
    for (int i = 0; i < 4; ++i) acc[i] = (f32x2){0.f, 0.f};
    gather_pipe(zb, col16, e0, md, sl, part, acc);

    unsigned outw[4] = {0, 0, 0, 0};
    if (active) {
        const unsigned* w = (const unsigned*)&vs;
        #pragma unroll
        for (int i2 = 0; i2 < 4; ++i2)
            acc[i2] += bf2_to_f32x2(w[i2]);   // zb pre-scaled: self term is zs[d]
        int f0 = sl << 3;
        #pragma unroll
        for (int i2 = 0; i2 < 4; ++i2) {
            int f = f0 + 2 * i2;
            float2 bv = *(const float2*)&bias[f];
            float2 gm = *(const float2*)&gamma[f];
            float2 bt = *(const float2*)&beta[f];
            float2 mn = *(const float2*)&mean[f];
            float2 vr = *(const float2*)&var[f];
            float vx = acc[i2].x * dd + bv.x;
            float vy = acc[i2].y * dd + bv.y;
            float sx = gm.x * rsqrtf(vr.x + BN_EPS);
            float sy = gm.y * rsqrtf(vr.y + BN_EPS);
            float rx = fmaxf((vx - mn.x) * sx + bt.x, 0.f);
            float ry = fmaxf((vy - mn.y) * sy + bt.y, 0.f);
            outw[i2] = pack_bf2(rx, ry);
        }
    }
    int local = wave * 4 + part;
    *(uint4*)&H1[local][sl << 3] = *(uint4*)outw;
    __syncthreads();

    int m = sl;
    int quad = part;
    short8 a2[4];
    #pragma unroll
    for (int kt = 0; kt < 4; ++kt)
        a2[kt] = *(const short8*)&H1[m][kt * 32 + quad * 8];

    f32x4 acc2[2];
    acc2[0] = (f32x4){0.f, 0.f, 0.f, 0.f};
    acc2[1] = (f32x4){0.f, 0.f, 0.f, 0.f};
    #pragma unroll
    for (int i = 0; i < 2; ++i) {
        int ct = wave * 2 + i;
        const unsigned short* wb = &wt2[(size_t)(ct * 16 + m) * 128 + quad * 8];
        #pragma unroll
        for (int kt = 0; kt < 4; ++kt) {
            short8 b = *(const short8*)(wb + kt * 32);
            acc2[i] = __builtin_amdgcn_mfma_f32_16x16x32_bf16(a2[kt], b, acc2[i], 0, 0, 0);
        }
    }
    int gr = blockIdx.x * 16 + quad * 4;
    float ds2[4];
    #pragma unroll
    for (int reg = 0; reg < 4; ++reg)
        ds2[reg] = (gr + reg < n) ? dis[gr + reg] : 0.f;
    #pragma unroll
    for (int i = 0; i < 2; ++i) {
        int col = (wave * 2 + i) * 16 + m;
        #pragma unroll
        for (int reg = 0; reg < 4; ++reg)
            C2[quad * 4 + reg][col] = bf16_1(acc2[i][reg] * ds2[reg]);
    }
    __syncthreads();
    {
        int r = t >> 4;
        int c8 = (t & 15) * 8;
        int grow = blockIdx.x * 16 + r;
        if (grow < n)
            *(uint4*)&hwsb2[(size_t)grow * 128 + c8] = *(const uint4*)&C2[r][c8];
    }
}

// ------- layer-2 agg + BN + ReLU + attention + logits; block=256, 16 nodes -------

__global__ __launch_bounds__(256, 3) void k_agg2_att_logit(const unsigned short* __restrict__ hwsb,
                                                           const int* __restrict__ row_ptr,
                                                           const int* __restrict__ degA,
                                                           const unsigned short* __restrict__ col16,
                                                           const float* __restrict__ dis,
                                                           const float* __restrict__ bias,
                                                           const float* __restrict__ gamma,
                                                           const float* __restrict__ beta,
                                                           const float* __restrict__ mean,
                                                           const float* __restrict__ var,
                                                           const int* __restrict__ batch,
                                                           const float* __restrict__ att_w,
                                                           const float* __restrict__ cls_w,
                                                           float* __restrict__ att_out,
                                                           float* __restrict__ logits, int n) {
    __shared__ int   sg[16];
    __shared__ float sv[16];
    int t = threadIdx.x;
    int wave = t >> 6, lane = t & 63;
    int sl = lane & 15, part = lane >> 4;
    int d = blockIdx.x * 16 + wave * 4 + part;
    bool active = (d < n);
    int e0 = 0, P = 0;
    if (active) {
        e0 = row_ptr[d];
        P = degA[d];
    }
    // preload self row, self dis, and batch id BEFORE the gather
    uint4 vs = make_uint4(0, 0, 0, 0);
    float dd = 0.f;
    int g = -1;
    if (active) {
        vs = *(const uint4*)(hwsb + ((size_t)d << 7) + (sl << 3));
        dd = dis[d];
        g = batch[d];
    }
    int md = P;
    md = max(md, __shfl_xor(md, 16));
    md = max(md, __shfl_xor(md, 32));

    f32x2 acc[4];
    #pragma unroll
    for (int i = 0; i < 4; ++i) acc[i] = (f32x2){0.f, 0.f};
    gather_pipe(hwsb, col16, e0, md, sl, part, acc);

    float contrib = 0.f;
    float p = 0.f, q = 0.f;
    if (active) {
        const unsigned* w = (const unsigned*)&vs;
        #pragma unroll
        for (int i2 = 0; i2 < 4; ++i2)
            acc[i2] += bf2_to_f32x2(w[i2]);
        float dd2 = dd;
        int f0 = sl << 3;
        #pragma unroll
        for (int i2 = 0; i2 < 4; ++i2) {
            int f = f0 + 2 * i2;
            float2 bv = *(const float2*)&bias[f];
            float2 gm = *(const float2*)&gamma[f];
            float2 bt = *(const float2*)&beta[f];
            float2 mn = *(const float2*)&mean[f];
            float2 vr = *(const float2*)&var[f];
            float vx = acc[i2].x * dd2 + bv.x;
            float vy = acc[i2].y * dd2 + bv.y;
            float sx = gm.x * rsqrtf(vr.x + BN_EPS);
            float sy = gm.y * rsqrtf(vr.y + BN_EPS);
            float rx = fmaxf((vx - mn.x) * sx + bt.x, 0.f);
            float ry = fmaxf((vy - mn.y) * sy + bt.y, 0.f);
            float2 aw = *(const float2*)&att_w[f];
            float2 cw = *(const float2*)&cls_w[f];
            p += rx * aw.x + ry * aw.y;
            q += rx * cw.x + ry * cw.y;
        }
    }
    #pragma unroll
    for (int off = 1; off < 16; off <<= 1) {
        p += __shfl_xor(p, off);
        q += __shfl_xor(q, off);
    }
    if (active) {
        float a = 1.f / (1.f + expf(-p));
        if (sl == 0) att_out[d] = a;
        contrib = a * q;
    }
    if (sl == 0) {
        sg[wave * 4 + part] = g;
        sv[wave * 4 + part] = contrib;
    }
    __syncthreads();
    if (t == 0) {
        int cur = -1;
        float acc2 = 0.f;
        #pragma unroll
        for (int i = 0; i < 16; ++i) {
            int gi = sg[i];
            if (gi < 0) continue;
            if (gi != cur) {
                if (cur >= 0) atomicAdd(&logits[cur], acc2);
                cur = gi;
                acc2 = 0.f;
            }
            acc2 += sv[i];
        }
        if (cur >= 0) atomicAdd(&logits[cur], acc2);
    }
}

// ---------------- launch ----------------

extern "C" void kernel_launch(void* const* d_in, const int* in_sizes, int n_in,
                              void* d_out, int out_size, void* d_ws, size_t ws_size,
                              hipStream_t stream) {
    const float* x   = (const float*)d_in[0];
    const int*   ei  = (const int*)d_in[1];
    const int*   bat = (const int*)d_in[2];
    const float* W1  = (const float*)d_in[3];
    const float* b1  = (const float*)d_in[4];
    const float* g1  = (const float*)d_in[5];
    const float* bt1 = (const float*)d_in[6];
    const float* mn1 = (const float*)d_in[7];
    const float* vr1 = (const float*)d_in[8];
    const float* W2  = (const float*)d_in[9];
    const float* b2  = (const float*)d_in[10];
    const float* g2  = (const float*)d_in[11];
    const float* bt2 = (const float*)d_in[12];
    const float* mn2 = (const float*)d_in[13];
    const float* vr2 = (const float*)d_in[14];
    const float* attw = (const float*)d_in[15];
    const float* clsw = (const float*)d_in[16];
    const float* clsb = (const float*)d_in[17];

    int E = in_sizes[1] / 2;
    int n = in_sizes[2];
    const int* src = ei;
    const int* dst = ei + E;
    int NB = (n + 255) >> 8;       // buckets of 256 nodes

    char* ws = (char*)d_ws;
    auto alloc = [&](size_t bytes) {
        void* p = (void*)ws;
        ws += (bytes + 255) & ~(size_t)255;
        return p;
    };
    int*            bcurP   = (int*)alloc(NBKT * 16 * 4);
    unsigned*       bpacked = (unsigned*)alloc((size_t)NBKT * CAPB * 4);
    int*            row_ptr = (int*)alloc((size_t)n * 4);
    int*            degA    = (int*)alloc((size_t)n * 4);
    unsigned short* col16   = (unsigned short*)alloc(((size_t)NBKT * CAPC + 1024) * 2);
    float*          dis     = (float*)alloc((size_t)n * 4);
    unsigned short* zb      = (unsigned short*)alloc((size_t)(n + 1) * 128 * 2);
    unsigned short* hwsb2   = (unsigned short*)alloc((size_t)(n + 1) * 128 * 2);
    unsigned short* wt1     = (unsigned short*)alloc(128 * 128 * 2);
    unsigned short* wt2     = (unsigned short*)alloc(128 * 128 * 2);

    float* out = (float*)d_out;
    int DB = (E + ETILE - 1) / ETILE;
    int gb = (n + 63) / 64;        // ALL gemm1 tiles ride with distribute
    int ab = (n + 15) / 16;

    k_prep0<<<3, 256, 0, stream>>>(W1, W2, wt1, wt2, bcurP, clsb, out, zb, hwsb2, n);
    k_dist_gemm1<<<DB + gb, 256, 0, stream>>>(src, dst, bcurP, bpacked, x, wt1, zb,
                                              E, n, DB);
    k_csr_scale<<<2 * NB, 256, 0, stream>>>(bpacked, bcurP, row_ptr, degA, dis,
                                            col16, zb, n, NB);
    k_agg1_gemm2<<<ab, 256, 0, stream>>>(zb, row_ptr, degA, col16, dis,
                                         b1, g1, bt1, mn1, vr1, wt2, hwsb2, n);
    k_agg2_att_logit<<<ab, 256, 0, stream>>>(hwsb2, row_ptr, degA, col16, dis,
                                             b2, g2, bt2, mn2, vr2, bat, attw, clsw,
                                             out + NG, out, n);
}